// Round 2
// baseline (449.364 us; speedup 1.0000x reference)
//
#include <hip/hip_runtime.h>

#define BB 512
#define NN 64
#define EE 64
#define DD 256
#define BND (BB * NN * DD)
#define NEGV (-9e15f)

__device__ __forceinline__ float lrelu(float v) { return v > 0.f ? v : 0.2f * v; }

// p1 = w2 @ a[D:], p2 = w2 @ a2[:D], p3 = w3 @ a2[D:], c0 = wc . a[:D]
__global__ void prep_kernel(const float* __restrict__ w2, const float* __restrict__ w3,
                            const float* __restrict__ a, const float* __restrict__ a2,
                            const float* __restrict__ wc, float* __restrict__ prep) {
    int k = threadIdx.x;  // 0..255
    float s1 = 0.f, s2 = 0.f, s3 = 0.f;
    for (int j = 0; j < DD; j++) {
        float w2v = w2[k * DD + j];
        s1 = fmaf(w2v, a[DD + j], s1);
        s2 = fmaf(w2v, a2[j], s2);
        s3 = fmaf(w3[k * DD + j], a2[DD + j], s3);
    }
    prep[k] = s1; prep[256 + k] = s2; prep[512 + k] = s3;
    __shared__ float red[256];
    red[k] = wc[k] * a[k];
    __syncthreads();
    for (int off = 128; off > 0; off >>= 1) {
        if (k < off) red[k] += red[k + off];
        __syncthreads();
    }
    if (k == 0) prep[768] = red[0];
}

// One workgroup per batch. layer==0: x = emb gather, writes x1 (f32) to out[0..BND).
// layer==1: x = out[0..BND) (read before any write, per-block disjoint), transfer
//           matmul with wtr, writes out[0..BND) and out[BND..2BND) = final x,
//           out[2BND..3BND) = emb2 gather.
__launch_bounds__(256)
__global__ void hgat_layer(const int* __restrict__ inputs, const int* __restrict__ HT,
                           const float* __restrict__ emb_w,
                           const float* x_in,            // aliases out (layer 1) - no restrict
                           const float* __restrict__ wtr,
                           const float* __restrict__ prep,
                           float* out,                   // no restrict (aliases x_in)
                           const float* __restrict__ emb2_w,
                           const int layer) {
    __shared__ float xs[NN][DD];        // 64KB : x (layer1: overwritten by x@w)
    __shared__ float edg[EE * 272];     // 68KB : quadrant-padded edge matrix / w tile
    __shared__ float Wm[64][65];        // 16.64KB attention weights
    __shared__ float pv1[DD], pv2[DD], pv3[DD];
    __shared__ float s1v[NN], t2v[NN], uv[EE];
    __shared__ unsigned long long mE[EE], mN[NN];
    __shared__ int idxs[NN];
    __shared__ float c0s;

    const int b = blockIdx.x;
    const int t = threadIdx.x;
    const int lane = t & 63;
    const int wid = t >> 6;
    const int n4 = t >> 2, q4 = t & 3;   // row / quadrant mapping for 256 threads

    // ---- phase A: prep vectors, indices, edge masks ----
    pv1[t] = prep[t]; pv2[t] = prep[256 + t]; pv3[t] = prep[512 + t];
    if (t == 0) c0s = prep[768];
    if (t < NN) idxs[t] = inputs[b * NN + t];
    for (int i = 0; i < 16; i++) {
        int e = wid * 16 + i;
        int h = HT[((size_t)b * EE + e) * NN + lane];
        unsigned long long m = __ballot(h > 0);
        if (lane == 0) mE[e] = m;
    }
    __syncthreads();

    // ---- phase B: node masks + stage x into LDS ----
    if (t < NN) {
        unsigned long long acc = 0ull;
        for (int e = 0; e < EE; e++) acc |= ((mE[e] >> t) & 1ull) << e;
        mN[t] = acc;
    }
    if (layer == 0) {
        for (int i = t; i < NN * 64; i += 256) {       // 64 float4 per row
            int n = i >> 6, c = i & 63;
            ((float4*)&xs[n][0])[c] = ((const float4*)(emb_w + (size_t)idxs[n] * DD))[c];
        }
    } else {
        const float4* src = (const float4*)(x_in + (size_t)b * NN * DD);
        float4* dst = (float4*)&xs[0][0];
        for (int i = t; i < NN * DD / 4; i += 256) dst[i] = src[i];
    }
    __syncthreads();

    // ---- phase C: score dots s1,t2 ----
    {
        float a1 = 0.f, a2s = 0.f;
        const float4* row = (const float4*)&xs[n4][q4 * 64];
        const float4* p1p = (const float4*)&pv1[q4 * 64];
        const float4* p2p = (const float4*)&pv2[q4 * 64];
        #pragma unroll
        for (int c = 0; c < 16; c++) {
            float4 v = row[c], p1 = p1p[c], p2 = p2p[c];
            a1 = fmaf(v.x, p1.x, fmaf(v.y, p1.y, fmaf(v.z, p1.z, fmaf(v.w, p1.w, a1))));
            a2s = fmaf(v.x, p2.x, fmaf(v.y, p2.y, fmaf(v.z, p2.z, fmaf(v.w, p2.w, a2s))));
        }
        a1 += __shfl_xor(a1, 1);  a1 += __shfl_xor(a1, 2);
        a2s += __shfl_xor(a2s, 1); a2s += __shfl_xor(a2s, 2);
        if (q4 == 0) { s1v[n4] = lrelu(c0s + a1); t2v[n4] = a2s; }
    }

    // ---- phase C2 (layer 1): xa = xs @ wtr, staged through edg as w-tile ----
    if (layer == 1) {
        float xacc[64];
        #pragma unroll
        for (int j = 0; j < 64; j++) xacc[j] = 0.f;
        for (int ch = 0; ch < 4; ch++) {
            for (int i = t; i < 64 * 64; i += 256) {   // stage 64 k-rows of w
                int r = i >> 6, c = i & 63;
                *(float4*)&edg[r * 272 + (c >> 4) * 68 + (c & 15) * 4] =
                    ((const float4*)(wtr + (size_t)(ch * 64 + r) * DD))[c];
            }
            __syncthreads();
            for (int kk = 0; kk < 64; kk += 4) {
                float4 xv = *(const float4*)&xs[n4][ch * 64 + kk];
                const float4* w0 = (const float4*)&edg[(kk + 0) * 272 + q4 * 68];
                const float4* w1 = (const float4*)&edg[(kk + 1) * 272 + q4 * 68];
                const float4* w2 = (const float4*)&edg[(kk + 2) * 272 + q4 * 68];
                const float4* w3 = (const float4*)&edg[(kk + 3) * 272 + q4 * 68];
                #pragma unroll
                for (int c = 0; c < 16; c++) {
                    float4 r0 = w0[c], r1 = w1[c], r2 = w2[c], r3 = w3[c];
                    xacc[c*4+0] = fmaf(xv.x, r0.x, fmaf(xv.y, r1.x, fmaf(xv.z, r2.x, fmaf(xv.w, r3.x, xacc[c*4+0]))));
                    xacc[c*4+1] = fmaf(xv.x, r0.y, fmaf(xv.y, r1.y, fmaf(xv.z, r2.y, fmaf(xv.w, r3.y, xacc[c*4+1]))));
                    xacc[c*4+2] = fmaf(xv.x, r0.z, fmaf(xv.y, r1.z, fmaf(xv.z, r2.z, fmaf(xv.w, r3.z, xacc[c*4+2]))));
                    xacc[c*4+3] = fmaf(xv.x, r0.w, fmaf(xv.y, r1.w, fmaf(xv.z, r2.w, fmaf(xv.w, r3.w, xacc[c*4+3]))));
                }
            }
            __syncthreads();
        }
        // all reads of xs complete (barrier above) -> overwrite with xa
        float* dstp = &xs[n4][q4 * 64];
        #pragma unroll
        for (int c = 0; c < 16; c++) {
            float4 o; o.x = xacc[c*4+0]; o.y = xacc[c*4+1]; o.z = xacc[c*4+2]; o.w = xacc[c*4+3];
            ((float4*)dstp)[c] = o;
        }
    }
    __syncthreads();   // covers s1v/t2v (layer 0) and xa writes (layer 1, with phase D's barrier)

    // ---- phase D: att_edge -> Wm[e][n] (softmax over n, masked) ----
    for (int i = 0; i < 16; i++) {
        int e = wid * 16 + i;
        bool msk = (mE[e] >> lane) & 1ull;
        float v = msk ? s1v[lane] : NEGV;
        float mx = v;
        #pragma unroll
        for (int off = 32; off > 0; off >>= 1) mx = fmaxf(mx, __shfl_xor(mx, off));
        float p = __expf(v - mx);
        float s = p;
        #pragma unroll
        for (int off = 32; off > 0; off >>= 1) s += __shfl_xor(s, off);
        Wm[e][lane] = p / s;
    }
    __syncthreads();

    // ---- phase E: edge = att_edge @ x_agg ; u = edge . p3 ----
    {
        float acc[64];   // acc[cc] holds logical chunk (cc + 4*q4) & 15
        #pragma unroll
        for (int j = 0; j < 64; j++) acc[j] = 0.f;
        const int rot = q4 * 4;
        for (int k = 0; k < NN; k++) {
            float wk = Wm[n4][k];
            const float4* row = (const float4*)&xs[k][q4 * 64];
            #pragma unroll
            for (int cc = 0; cc < 16; cc++) {
                float4 v = row[(cc + rot) & 15];
                acc[cc*4+0] = fmaf(wk, v.x, acc[cc*4+0]);
                acc[cc*4+1] = fmaf(wk, v.y, acc[cc*4+1]);
                acc[cc*4+2] = fmaf(wk, v.z, acc[cc*4+2]);
                acc[cc*4+3] = fmaf(wk, v.w, acc[cc*4+3]);
            }
        }
        float ue = 0.f;
        #pragma unroll
        for (int cc = 0; cc < 16; cc++) {
            int c = (cc + rot) & 15;
            float4 o; o.x = acc[cc*4+0]; o.y = acc[cc*4+1]; o.z = acc[cc*4+2]; o.w = acc[cc*4+3];
            *(float4*)&edg[n4 * 272 + q4 * 68 + c * 4] = o;
            const float* p3 = &pv3[q4 * 64 + c * 4];
            ue = fmaf(o.x, p3[0], fmaf(o.y, p3[1], fmaf(o.z, p3[2], fmaf(o.w, p3[3], ue))));
        }
        ue += __shfl_xor(ue, 1); ue += __shfl_xor(ue, 2);
        if (q4 == 0) uv[n4] = ue;
    }
    __syncthreads();

    // ---- phase F: att_node -> Wm[n][e] (softmax over e, masked) ----
    for (int i = 0; i < 16; i++) {
        int n = wid * 16 + i;
        float tn = t2v[n];
        float sv = lrelu(tn + uv[lane]);
        bool msk = (mN[n] >> lane) & 1ull;
        float v = msk ? sv : NEGV;
        float mx = v;
        #pragma unroll
        for (int off = 32; off > 0; off >>= 1) mx = fmaxf(mx, __shfl_xor(mx, off));
        float p = __expf(v - mx);
        float s = p;
        #pragma unroll
        for (int off = 32; off > 0; off >>= 1) s += __shfl_xor(s, off);
        Wm[n][lane] = p / s;
    }
    __syncthreads();

    // ---- phase G: node = att_node @ edge ; + residual ; write ----
    {
        float acc[64];
        #pragma unroll
        for (int j = 0; j < 64; j++) acc[j] = 0.f;
        for (int k = 0; k < EE; k++) {
            float wk = Wm[n4][k];
            const float4* row = (const float4*)&edg[k * 272 + q4 * 68];
            #pragma unroll
            for (int c = 0; c < 16; c++) {
                float4 v = row[c];
                acc[c*4+0] = fmaf(wk, v.x, acc[c*4+0]);
                acc[c*4+1] = fmaf(wk, v.y, acc[c*4+1]);
                acc[c*4+2] = fmaf(wk, v.z, acc[c*4+2]);
                acc[c*4+3] = fmaf(wk, v.w, acc[c*4+3]);
            }
        }
        if (layer == 0) {
            float* dst = out + ((size_t)(b * NN + n4)) * DD + q4 * 64;
            const float4* xr = (const float4*)&xs[n4][q4 * 64];
            #pragma unroll
            for (int c = 0; c < 16; c++) {
                float4 r = xr[c];
                float4 o; o.x = acc[c*4+0] + r.x; o.y = acc[c*4+1] + r.y;
                o.z = acc[c*4+2] + r.z; o.w = acc[c*4+3] + r.w;
                ((float4*)dst)[c] = o;
            }
        } else {
            const float4* er = (const float4*)(emb_w + (size_t)idxs[n4] * DD + q4 * 64);
            size_t base = ((size_t)(b * NN + n4)) * DD + q4 * 64;
            #pragma unroll
            for (int c = 0; c < 16; c++) {
                float4 r = er[c];
                float4 o; o.x = acc[c*4+0] + r.x; o.y = acc[c*4+1] + r.y;
                o.z = acc[c*4+2] + r.z; o.w = acc[c*4+3] + r.w;
                ((float4*)(out + base))[c] = o;
                ((float4*)(out + BND + base))[c] = o;
            }
        }
    }
    // ---- nodes2 gather copy (layer 1 only) ----
    if (layer == 1) {
        for (int i = t; i < NN * 64; i += 256) {
            int n = i >> 6, c = i & 63;
            float4 v = ((const float4*)(emb2_w + (size_t)idxs[n] * DD))[c];
            ((float4*)(out + (size_t)2 * BND + (size_t)(b * NN + n) * DD))[c] = v;
        }
    }
}

extern "C" void kernel_launch(void* const* d_in, const int* in_sizes, int n_in,
                              void* d_out, int out_size, void* d_ws, size_t ws_size,
                              hipStream_t stream) {
    const int* inputs = (const int*)d_in[0];
    const int* HT = (const int*)d_in[1];
    // d_in[2]=G, d_in[3]=EG unused
    const float* emb_w  = (const float*)d_in[4];
    const float* emb2_w = (const float*)d_in[5];
    const float* g1_w2 = (const float*)d_in[6];
    const float* g1_w3 = (const float*)d_in[7];
    const float* g1_a  = (const float*)d_in[8];
    const float* g1_a2 = (const float*)d_in[9];
    const float* g1_wc = (const float*)d_in[10];
    const float* g2_w  = (const float*)d_in[11];
    const float* g2_w2 = (const float*)d_in[12];
    const float* g2_w3 = (const float*)d_in[13];
    const float* g2_a  = (const float*)d_in[14];
    const float* g2_a2 = (const float*)d_in[15];
    const float* g2_wc = (const float*)d_in[16];

    float* out = (float*)d_out;
    float* prep = (float*)d_ws;   // 2 x 1024 floats

    prep_kernel<<<1, 256, 0, stream>>>(g1_w2, g1_w3, g1_a, g1_a2, g1_wc, prep);
    prep_kernel<<<1, 256, 0, stream>>>(g2_w2, g2_w3, g2_a, g2_a2, g2_wc, prep + 1024);

    // layer 1: x1 = gat1(emb) + emb   -> out[0..BND)
    hgat_layer<<<BB, 256, 0, stream>>>(inputs, HT, emb_w, nullptr, nullptr,
                                       prep, out, nullptr, 0);
    // layer 2: x = gat2(x1) + emb -> out[0..BND), out[BND..2BND); nodes2 -> out[2BND..)
    hgat_layer<<<BB, 256, 0, stream>>>(inputs, HT, emb_w, out, g2_w,
                                       prep + 1024, out, emb2_w, 1);
}

// Round 3
// 240.171 us; speedup vs baseline: 1.8710x; 1.8710x over previous
//
#include <hip/hip_runtime.h>

#define BB 512
#define NN 64
#define EE 64
#define DD 256
#define BND (BB * NN * DD)
#define NEGV (-9e15f)

typedef __attribute__((ext_vector_type(8))) short s8v;
typedef __attribute__((ext_vector_type(4))) float f4v;
typedef __attribute__((ext_vector_type(8))) unsigned short u16x8;

__device__ __forceinline__ unsigned short f2bf(float f) {
    unsigned int x = __float_as_uint(f);
    x = x + 0x7fffu + ((x >> 16) & 1u);   // RNE
    return (unsigned short)(x >> 16);
}
__device__ __forceinline__ float lrelu(float v) { return v > 0.f ? v : 0.2f * v; }
__device__ __forceinline__ float4 fma4(float s, float4 a, float4 c) {
    float4 r; r.x = fmaf(s, a.x, c.x); r.y = fmaf(s, a.y, c.y);
    r.z = fmaf(s, a.z, c.z); r.w = fmaf(s, a.w, c.w); return r;
}

// prep: p1a,p2a,p3a,c0a (layer1) ; p1b,p2b,wp3b,c0b (layer2)
// layout (floats): [0)p1a [256)p2a [512)p3a [768]c0a [1024)p1b [1280)p2b [1536)wp3b [1792]c0b
__global__ void prep_kernel(const float* __restrict__ w2a, const float* __restrict__ w3a,
                            const float* __restrict__ aa, const float* __restrict__ a2a,
                            const float* __restrict__ wca,
                            const float* __restrict__ w2b, const float* __restrict__ w3b,
                            const float* __restrict__ ab, const float* __restrict__ a2b,
                            const float* __restrict__ wcb,
                            const float* __restrict__ wtr, float* __restrict__ prep) {
    int k = threadIdx.x;
    __shared__ float sh[256];
    __shared__ float p3b[256];
    float s1 = 0.f, s2 = 0.f, s3 = 0.f;
    for (int j = 0; j < DD; j++) {
        float v = w2a[k * DD + j];
        s1 = fmaf(v, aa[DD + j], s1);
        s2 = fmaf(v, a2a[j], s2);
        s3 = fmaf(w3a[k * DD + j], a2a[DD + j], s3);
    }
    prep[k] = s1; prep[256 + k] = s2; prep[512 + k] = s3;
    sh[k] = wca[k] * aa[k];
    __syncthreads();
    for (int o = 128; o > 0; o >>= 1) { if (k < o) sh[k] += sh[k + o]; __syncthreads(); }
    if (k == 0) prep[768] = sh[0];
    __syncthreads();
    s1 = 0.f; s2 = 0.f; s3 = 0.f;
    for (int j = 0; j < DD; j++) {
        float v = w2b[k * DD + j];
        s1 = fmaf(v, ab[DD + j], s1);
        s2 = fmaf(v, a2b[j], s2);
        s3 = fmaf(w3b[k * DD + j], a2b[DD + j], s3);
    }
    prep[1024 + k] = s1; prep[1280 + k] = s2; p3b[k] = s3;
    sh[k] = wcb[k] * ab[k];
    __syncthreads();
    for (int o = 128; o > 0; o >>= 1) { if (k < o) sh[k] += sh[k + o]; __syncthreads(); }
    if (k == 0) prep[1792] = sh[0];
    __syncthreads();
    float s = 0.f;
    for (int j = 0; j < DD; j++) s = fmaf(wtr[k * DD + j], p3b[j], s);
    prep[1536 + k] = s;
}

// pack w (g2_w) into MFMA B-fragment-linear bf16: frag (kc,nt), lane l holds
// B[k = kc*32+(l>>4)*8+j][n = nt*16+(l&15)], j=0..7, at wfrag[(frag*64+l)*8+j]
__global__ void pack_w(const float* __restrict__ wtr, unsigned short* __restrict__ wfrag) {
    int gid = blockIdx.x * 256 + threadIdx.x;   // 0..8191
    int l = gid & 63, frag = gid >> 6;
    int kc = frag >> 4, nt = frag & 15;
    int kb = kc * 32 + (l >> 4) * 8;
    int n = nt * 16 + (l & 15);
    u16x8 u;
    #pragma unroll
    for (int j = 0; j < 8; j++) u[j] = f2bf(wtr[(size_t)(kb + j) * DD + n]);
    *(u16x8*)(wfrag + (size_t)gid * 8) = u;
}

// LDS pool offsets (floats)
#define X0_OF 0        // x0: 64 x 260 f32
#define CB_OF 16640    // C1': 64 x 68
#define MB_OF 20992    // attE / M: 64 x 68
#define AN_OF 25344    // attN: 64 x 68
#define DB_OF 29696    // C2: 64 x 68
#define TB_OF 25344    // Tb bf16 64 x 264 (overlays attN+C2; used after both dead)
#define PV_OF 34048    // pvs 6 x 256
#define DV_OF 35584    // dv  6 x 64
#define D2_OF 35968    // db2 3 x 64
#define UU_OF 36160    // uu 64
#define ME_OF 36224    // mE (ull[64])
#define MN_OF 36352    // mN (ull[64])
#define POOL_FLOATS 36480   // 142.5 KB

__launch_bounds__(256)
__global__ void hgat_fused(const int* __restrict__ inputs, const int* __restrict__ HT,
                           const float* __restrict__ emb_w, const float* __restrict__ emb2_w,
                           const float* __restrict__ prep, const unsigned short* __restrict__ wfrag,
                           float* __restrict__ out) {
    __shared__ float pool[POOL_FLOATS];
    float* x0f = pool + X0_OF;
    float* Cb  = pool + CB_OF;
    float* Mb  = pool + MB_OF;
    float* An  = pool + AN_OF;
    float* Db  = pool + DB_OF;
    unsigned short* Tb = (unsigned short*)(pool + TB_OF);
    float* pvs = pool + PV_OF;
    float* dv  = pool + DV_OF;
    float* db2 = pool + D2_OF;
    float* uu  = pool + UU_OF;
    unsigned long long* mE = (unsigned long long*)(pool + ME_OF);
    unsigned long long* mN = (unsigned long long*)(pool + MN_OF);

    const int b = blockIdx.x;
    const int t = threadIdx.x;
    const int lane = t & 63;
    const int wid = t >> 6;
    const int n4 = t >> 2, q4 = t & 3;

    // ---- phase 0: pvs, x0 stage, edge masks ----
    {
        const int off[6] = {0, 256, 512, 1024, 1280, 1536};
        #pragma unroll
        for (int j = 0; j < 6; j++) pvs[j * 256 + t] = prep[off[j] + t];
    }
    for (int i = t; i < 64 * 64; i += 256) {
        int n = i >> 6, c = i & 63;
        int idx = inputs[b * 64 + n];
        *(float4*)&x0f[n * 260 + c * 4] = ((const float4*)(emb_w + (size_t)idx * DD))[c];
    }
    for (int i = 0; i < 16; i++) {
        int e = wid * 16 + i;
        int h = HT[((size_t)b * EE + e) * NN + lane];
        unsigned long long m = __ballot(h > 0);
        if (lane == 0) mE[e] = m;
    }
    __syncthreads();
    if (t < 64) {
        unsigned long long acc = 0ull;
        for (int e = 0; e < 64; e++) acc |= ((mE[e] >> t) & 1ull) << e;
        mN[t] = acc;
    }

    // ---- phase 1: six dots of x0 rows with p-vectors ----
    {
        float a6[6] = {0.f, 0.f, 0.f, 0.f, 0.f, 0.f};
        const float* xr = &x0f[n4 * 260 + q4 * 64];
        const float* pb = &pvs[q4 * 64];
        #pragma unroll
        for (int cc = 0; cc < 16; cc++) {
            float4 xv = *(const float4*)&xr[cc * 4];
            #pragma unroll
            for (int j = 0; j < 6; j++) {
                float4 p = *(const float4*)&pb[j * 256 + cc * 4];
                a6[j] = fmaf(xv.x, p.x, fmaf(xv.y, p.y, fmaf(xv.z, p.z, fmaf(xv.w, p.w, a6[j]))));
            }
        }
        #pragma unroll
        for (int j = 0; j < 6; j++) {
            a6[j] += __shfl_xor(a6[j], 1);
            a6[j] += __shfl_xor(a6[j], 2);
        }
        if (q4 == 0) {
            #pragma unroll
            for (int j = 0; j < 6; j++) dv[j * 64 + n4] = a6[j];
        }
    }
    __syncthreads();

    // ---- phase 2: attE1 -> Mb ----
    {
        float c0a = prep[768];
        float s1n = lrelu(c0a + dv[lane]);
        for (int i = 0; i < 16; i++) {
            int e = wid * 16 + i;
            bool msk = (mE[e] >> lane) & 1ull;
            float v = msk ? s1n : NEGV;
            float mx = v;
            #pragma unroll
            for (int o = 32; o > 0; o >>= 1) mx = fmaxf(mx, __shfl_xor(mx, o));
            float p = __expf(v - mx), s = p;
            #pragma unroll
            for (int o = 32; o > 0; o >>= 1) s += __shfl_xor(s, o);
            Mb[e * 68 + lane] = p / s;
        }
    }
    __syncthreads();

    // ---- phase 3: u1 = attE1 . dv[2] ----
    {
        float s = 0.f;
        #pragma unroll
        for (int c = 0; c < 4; c++) {
            float4 av = *(const float4*)&Mb[n4 * 68 + q4 * 16 + c * 4];
            float4 dd = *(const float4*)&dv[2 * 64 + q4 * 16 + c * 4];
            s = fmaf(av.x, dd.x, fmaf(av.y, dd.y, fmaf(av.z, dd.z, fmaf(av.w, dd.w, s))));
        }
        s += __shfl_xor(s, 1); s += __shfl_xor(s, 2);
        if (q4 == 0) uu[n4] = s;
    }
    __syncthreads();

    // ---- phase 4: attN1 -> An ----
    {
        float ul = uu[lane];
        for (int i = 0; i < 16; i++) {
            int n = wid * 16 + i;
            float sv = lrelu(dv[64 + n] + ul);
            bool msk = (mN[n] >> lane) & 1ull;
            float v = msk ? sv : NEGV;
            float mx = v;
            #pragma unroll
            for (int o = 32; o > 0; o >>= 1) mx = fmaxf(mx, __shfl_xor(mx, o));
            float p = __expf(v - mx), s = p;
            #pragma unroll
            for (int o = 32; o > 0; o >>= 1) s += __shfl_xor(s, o);
            An[n * 68 + lane] = p / s;
        }
    }
    __syncthreads();

    // ---- phase 5: C1' = attN1@attE1 + I -> Cb ----
    {
        float4 acc[4] = {{0,0,0,0},{0,0,0,0},{0,0,0,0},{0,0,0,0}};
        for (int e0 = 0; e0 < 64; e0 += 4) {
            float4 wn = *(const float4*)&An[n4 * 68 + e0];
            float wa[4] = {wn.x, wn.y, wn.z, wn.w};
            #pragma unroll
            for (int rr = 0; rr < 4; rr++) {
                const float4* er = (const float4*)&Mb[(e0 + rr) * 68 + q4 * 16];
                #pragma unroll
                for (int c = 0; c < 4; c++) acc[c] = fma4(wa[rr], er[c], acc[c]);
            }
        }
        #pragma unroll
        for (int c = 0; c < 4; c++) {
            float av[4] = {acc[c].x, acc[c].y, acc[c].z, acc[c].w};
            float4 o;
            o.x = av[0] + ((q4 * 16 + c * 4 + 0) == n4 ? 1.f : 0.f);
            o.y = av[1] + ((q4 * 16 + c * 4 + 1) == n4 ? 1.f : 0.f);
            o.z = av[2] + ((q4 * 16 + c * 4 + 2) == n4 ? 1.f : 0.f);
            o.w = av[3] + ((q4 * 16 + c * 4 + 3) == n4 ? 1.f : 0.f);
            *(float4*)&Cb[n4 * 68 + q4 * 16 + c * 4] = o;
        }
    }
    __syncthreads();

    // ---- phase 6: db2[j] = C1' @ dv[3+j] ----
    {
        float s0 = 0.f, s1 = 0.f, s2 = 0.f;
        #pragma unroll
        for (int c = 0; c < 4; c++) {
            float4 cv = *(const float4*)&Cb[n4 * 68 + q4 * 16 + c * 4];
            float4 d0 = *(const float4*)&dv[3 * 64 + q4 * 16 + c * 4];
            float4 d1 = *(const float4*)&dv[4 * 64 + q4 * 16 + c * 4];
            float4 d2 = *(const float4*)&dv[5 * 64 + q4 * 16 + c * 4];
            s0 = fmaf(cv.x, d0.x, fmaf(cv.y, d0.y, fmaf(cv.z, d0.z, fmaf(cv.w, d0.w, s0))));
            s1 = fmaf(cv.x, d1.x, fmaf(cv.y, d1.y, fmaf(cv.z, d1.z, fmaf(cv.w, d1.w, s1))));
            s2 = fmaf(cv.x, d2.x, fmaf(cv.y, d2.y, fmaf(cv.z, d2.z, fmaf(cv.w, d2.w, s2))));
        }
        s0 += __shfl_xor(s0, 1); s0 += __shfl_xor(s0, 2);
        s1 += __shfl_xor(s1, 1); s1 += __shfl_xor(s1, 2);
        s2 += __shfl_xor(s2, 1); s2 += __shfl_xor(s2, 2);
        if (q4 == 0) { db2[n4] = s0; db2[64 + n4] = s1; db2[128 + n4] = s2; }
    }
    __syncthreads();

    // ---- phase 7: attE2 -> Mb ----
    {
        float c0b = prep[1792];
        float s1n = lrelu(c0b + db2[lane]);
        for (int i = 0; i < 16; i++) {
            int e = wid * 16 + i;
            bool msk = (mE[e] >> lane) & 1ull;
            float v = msk ? s1n : NEGV;
            float mx = v;
            #pragma unroll
            for (int o = 32; o > 0; o >>= 1) mx = fmaxf(mx, __shfl_xor(mx, o));
            float p = __expf(v - mx), s = p;
            #pragma unroll
            for (int o = 32; o > 0; o >>= 1) s += __shfl_xor(s, o);
            Mb[e * 68 + lane] = p / s;
        }
    }
    __syncthreads();

    // ---- phase 8: u2 = attE2 . db2[2] ----
    {
        float s = 0.f;
        #pragma unroll
        for (int c = 0; c < 4; c++) {
            float4 av = *(const float4*)&Mb[n4 * 68 + q4 * 16 + c * 4];
            float4 dd = *(const float4*)&db2[2 * 64 + q4 * 16 + c * 4];
            s = fmaf(av.x, dd.x, fmaf(av.y, dd.y, fmaf(av.z, dd.z, fmaf(av.w, dd.w, s))));
        }
        s += __shfl_xor(s, 1); s += __shfl_xor(s, 2);
        if (q4 == 0) uu[n4] = s;
    }
    __syncthreads();

    // ---- phase 9: attN2 -> An ----
    {
        float ul = uu[lane];
        for (int i = 0; i < 16; i++) {
            int n = wid * 16 + i;
            float sv = lrelu(db2[64 + n] + ul);
            bool msk = (mN[n] >> lane) & 1ull;
            float v = msk ? sv : NEGV;
            float mx = v;
            #pragma unroll
            for (int o = 32; o > 0; o >>= 1) mx = fmaxf(mx, __shfl_xor(mx, o));
            float p = __expf(v - mx), s = p;
            #pragma unroll
            for (int o = 32; o > 0; o >>= 1) s += __shfl_xor(s, o);
            An[n * 68 + lane] = p / s;
        }
    }
    __syncthreads();

    // ---- phase 10: C2 = attN2@attE2 -> Db ----
    {
        float4 acc[4] = {{0,0,0,0},{0,0,0,0},{0,0,0,0},{0,0,0,0}};
        for (int e0 = 0; e0 < 64; e0 += 4) {
            float4 wn = *(const float4*)&An[n4 * 68 + e0];
            float wa[4] = {wn.x, wn.y, wn.z, wn.w};
            #pragma unroll
            for (int rr = 0; rr < 4; rr++) {
                const float4* er = (const float4*)&Mb[(e0 + rr) * 68 + q4 * 16];
                #pragma unroll
                for (int c = 0; c < 4; c++) acc[c] = fma4(wa[rr], er[c], acc[c]);
            }
        }
        #pragma unroll
        for (int c = 0; c < 4; c++) *(float4*)&Db[n4 * 68 + q4 * 16 + c * 4] = acc[c];
    }
    __syncthreads();

    // ---- phase 11: M = C2 @ C1' -> Mb ----
    {
        float4 acc[4] = {{0,0,0,0},{0,0,0,0},{0,0,0,0},{0,0,0,0}};
        for (int e0 = 0; e0 < 64; e0 += 4) {
            float4 wn = *(const float4*)&Db[n4 * 68 + e0];
            float wa[4] = {wn.x, wn.y, wn.z, wn.w};
            #pragma unroll
            for (int rr = 0; rr < 4; rr++) {
                const float4* er = (const float4*)&Cb[(e0 + rr) * 68 + q4 * 16];
                #pragma unroll
                for (int c = 0; c < 4; c++) acc[c] = fma4(wa[rr], er[c], acc[c]);
            }
        }
        #pragma unroll
        for (int c = 0; c < 4; c++) *(float4*)&Mb[n4 * 68 + q4 * 16 + c * 4] = acc[c];
    }
    __syncthreads();

    // ---- phase 12: T = M @ x0 (f32), convert -> Tb bf16 (overlays An+Db) ----
    {
        const int n16 = t >> 4, c16 = t & 15;
        const int rot = c16 >> 1;
        float4 acc[4][4];
        #pragma unroll
        for (int rr = 0; rr < 4; rr++)
            #pragma unroll
            for (int cc = 0; cc < 4; cc++) acc[rr][cc] = make_float4(0.f, 0.f, 0.f, 0.f);
        for (int k0 = 0; k0 < 64; k0 += 4) {
            float ma[4][4];
            #pragma unroll
            for (int rr = 0; rr < 4; rr++) {
                float4 m = *(const float4*)&Mb[(n16 * 4 + rr) * 68 + k0];
                ma[rr][0] = m.x; ma[rr][1] = m.y; ma[rr][2] = m.z; ma[rr][3] = m.w;
            }
            #pragma unroll
            for (int kk = 0; kk < 4; kk++) {
                #pragma unroll
                for (int cc = 0; cc < 4; cc++) {
                    int c = (cc + rot) & 3;
                    float4 xv = *(const float4*)&x0f[(k0 + kk) * 260 + c16 * 16 + c * 4];
                    #pragma unroll
                    for (int rr = 0; rr < 4; rr++) acc[rr][cc] = fma4(ma[rr][kk], xv, acc[rr][cc]);
                }
            }
        }
        __syncthreads();   // An/Db fully read (phases 10/11 done) before Tb overwrite
        #pragma unroll
        for (int rr = 0; rr < 4; rr++) {
            int r = n16 * 4 + rr;
            #pragma unroll
            for (int cc = 0; cc < 4; cc++) {
                int c = (cc + rot) & 3;
                float4 v = acc[rr][cc];
                ushort4 u;
                u.x = f2bf(v.x); u.y = f2bf(v.y); u.z = f2bf(v.z); u.w = f2bf(v.w);
                *(ushort4*)&Tb[r * 264 + c16 * 16 + c * 4] = u;
            }
        }
    }
    __syncthreads();

    // ---- phase 13: out = Tb @ wfrag (MFMA bf16) + x0 residual ----
    {
        const int l = lane;
        const int r = wid * 16 + (l & 15);
        const int kh = l >> 4;
        f4v acc[16];
        #pragma unroll
        for (int nt = 0; nt < 16; nt++) acc[nt] = (f4v){0.f, 0.f, 0.f, 0.f};
        const s8v* wf = (const s8v*)wfrag;
        #pragma unroll
        for (int kc = 0; kc < 8; kc++) {
            s8v a = *(const s8v*)&Tb[r * 264 + kc * 32 + kh * 8];
            #pragma unroll
            for (int nt = 0; nt < 16; nt++) {
                s8v bv = wf[(kc * 16 + nt) * 64 + l];
                acc[nt] = __builtin_amdgcn_mfma_f32_16x16x32_bf16(a, bv, acc[nt], 0, 0, 0);
            }
        }
        const int orow = wid * 16 + kh * 4;
        const int ocol = l & 15;
        #pragma unroll
        for (int nt = 0; nt < 16; nt++) {
            #pragma unroll
            for (int rg = 0; rg < 4; rg++) {
                int row = orow + rg;
                int col = nt * 16 + ocol;
                float v = acc[nt][rg] + x0f[row * 260 + col];
                size_t o = (size_t)(b * 64 + row) * 256 + col;
                out[o] = v;
                out[BND + o] = v;
            }
        }
    }

    // ---- phase 14: nodes2 = emb2 gather ----
    for (int i = t; i < 64 * 64; i += 256) {
        int n = i >> 6, c = i & 63;
        int idx = inputs[b * 64 + n];
        float4 v = ((const float4*)(emb2_w + (size_t)idx * DD))[c];
        ((float4*)(out + (size_t)2 * BND + (size_t)(b * 64 + n) * DD))[c] = v;
    }
}

extern "C" void kernel_launch(void* const* d_in, const int* in_sizes, int n_in,
                              void* d_out, int out_size, void* d_ws, size_t ws_size,
                              hipStream_t stream) {
    const int* inputs = (const int*)d_in[0];
    const int* HT = (const int*)d_in[1];
    const float* emb_w  = (const float*)d_in[4];
    const float* emb2_w = (const float*)d_in[5];
    const float* g1_w2 = (const float*)d_in[6];
    const float* g1_w3 = (const float*)d_in[7];
    const float* g1_a  = (const float*)d_in[8];
    const float* g1_a2 = (const float*)d_in[9];
    const float* g1_wc = (const float*)d_in[10];
    const float* g2_w  = (const float*)d_in[11];
    const float* g2_w2 = (const float*)d_in[12];
    const float* g2_w3 = (const float*)d_in[13];
    const float* g2_a  = (const float*)d_in[14];
    const float* g2_a2 = (const float*)d_in[15];
    const float* g2_wc = (const float*)d_in[16];

    float* out = (float*)d_out;
    float* prep = (float*)d_ws;                                  // 2048 floats
    unsigned short* wfrag = (unsigned short*)((char*)d_ws + 8192); // 65536 bf16

    prep_kernel<<<1, 256, 0, stream>>>(g1_w2, g1_w3, g1_a, g1_a2, g1_wc,
                                       g2_w2, g2_w3, g2_a, g2_a2, g2_wc,
                                       g2_w, prep);
    pack_w<<<32, 256, 0, stream>>>(g2_w, wfrag);
    hgat_fused<<<BB, 256, 0, stream>>>(inputs, HT, emb_w, emb2_w, prep, wfrag, out);
}

// Round 4
// 173.788 us; speedup vs baseline: 2.5857x; 1.3820x over previous
//
#include <hip/hip_runtime.h>

#define BB 512
#define NN 64
#define EE 64
#define DD 256
#define BND (BB * NN * DD)
#define NEGV (-9e15f)

typedef __attribute__((ext_vector_type(8))) short s8v;
typedef __attribute__((ext_vector_type(4))) float f4v;
typedef __attribute__((ext_vector_type(8))) unsigned short u16x8;

__device__ __forceinline__ unsigned short f2bf(float f) {
    unsigned int x = __float_as_uint(f);
    x = x + 0x7fffu + ((x >> 16) & 1u);   // RNE
    return (unsigned short)(x >> 16);
}
__device__ __forceinline__ float lrelu(float v) { return v > 0.f ? v : 0.2f * v; }
__device__ __forceinline__ float4 fma4(float s, float4 a, float4 c) {
    float4 r; r.x = fmaf(s, a.x, c.x); r.y = fmaf(s, a.y, c.y);
    r.z = fmaf(s, a.z, c.z); r.w = fmaf(s, a.w, c.w); return r;
}

// ws byte offsets
#define WS_PREP  0          // 2048 f32
#define WS_WFRAG 8192       // 65536 bf16
#define WS_DV    139264     // 512*384 f32
#define WS_M     925696     // 512*4096 bf16
#define WS_X0    5120000    // 512*64*256 bf16

// prep layout (floats): [0)p1a [256)p2a [512)p3a [768]c0a [1024)p1b [1280)p2b [1536)wp3b [1792]c0b
__global__ void prep_kernel(const float* __restrict__ w2a, const float* __restrict__ w3a,
                            const float* __restrict__ aa, const float* __restrict__ a2a,
                            const float* __restrict__ wca,
                            const float* __restrict__ w2b, const float* __restrict__ w3b,
                            const float* __restrict__ ab, const float* __restrict__ a2b,
                            const float* __restrict__ wcb,
                            const float* __restrict__ wtr, float* __restrict__ prep) {
    int k = threadIdx.x;
    __shared__ float sh[256];
    __shared__ float p3b[256];
    float s1 = 0.f, s2 = 0.f, s3 = 0.f;
    for (int j = 0; j < DD; j++) {
        float v = w2a[k * DD + j];
        s1 = fmaf(v, aa[DD + j], s1);
        s2 = fmaf(v, a2a[j], s2);
        s3 = fmaf(w3a[k * DD + j], a2a[DD + j], s3);
    }
    prep[k] = s1; prep[256 + k] = s2; prep[512 + k] = s3;
    sh[k] = wca[k] * aa[k];
    __syncthreads();
    for (int o = 128; o > 0; o >>= 1) { if (k < o) sh[k] += sh[k + o]; __syncthreads(); }
    if (k == 0) prep[768] = sh[0];
    __syncthreads();
    s1 = 0.f; s2 = 0.f; s3 = 0.f;
    for (int j = 0; j < DD; j++) {
        float v = w2b[k * DD + j];
        s1 = fmaf(v, ab[DD + j], s1);
        s2 = fmaf(v, a2b[j], s2);
        s3 = fmaf(w3b[k * DD + j], a2b[DD + j], s3);
    }
    prep[1024 + k] = s1; prep[1280 + k] = s2; p3b[k] = s3;
    sh[k] = wcb[k] * ab[k];
    __syncthreads();
    for (int o = 128; o > 0; o >>= 1) { if (k < o) sh[k] += sh[k + o]; __syncthreads(); }
    if (k == 0) prep[1792] = sh[0];
    __syncthreads();
    float s = 0.f;
    for (int j = 0; j < DD; j++) s = fmaf(wtr[k * DD + j], p3b[j], s);
    prep[1536 + k] = s;
}

// pack g2_w into MFMA B-fragments: frag(kc,nt): lane l holds B[kc*32+(l>>4)*8+j][nt*16+(l&15)]
__global__ void pack_w(const float* __restrict__ wtr, unsigned short* __restrict__ wfrag) {
    int gid = blockIdx.x * 256 + threadIdx.x;   // 0..8191
    int l = gid & 63, frag = gid >> 6;
    int kc = frag >> 4, nt = frag & 15;
    int kb = kc * 32 + (l >> 4) * 8;
    int n = nt * 16 + (l & 15);
    u16x8 u;
    #pragma unroll
    for (int j = 0; j < 8; j++) u[j] = f2bf(wtr[(size_t)(kb + j) * DD + n]);
    *(u16x8*)(wfrag + (size_t)gid * 8) = u;
}

// K1: per half-batch: emb gather -> dv (6 dots), x0 bf16, nodes2 copy
__launch_bounds__(256)
__global__ void k1_stage(const int* __restrict__ inputs,
                         const float* __restrict__ emb_w, const float* __restrict__ emb2_w,
                         const float* __restrict__ prep,
                         float* __restrict__ dv, unsigned short* __restrict__ x0bf,
                         float* __restrict__ out) {
    __shared__ float pvs[6 * 256];
    const int t = threadIdx.x;
    const int b = blockIdx.x >> 1;
    const int half = blockIdx.x & 1;
    {
        const int off[6] = {0, 256, 512, 1024, 1280, 1536};
        #pragma unroll
        for (int j = 0; j < 6; j++) pvs[j * 256 + t] = prep[off[j] + t];
    }
    const int n = half * 32 + (t >> 3);
    const int q8 = t & 7;
    const int idx = inputs[b * 64 + n];
    __syncthreads();
    float xf[32];
    {
        const float4* src = (const float4*)(emb_w + (size_t)idx * DD + q8 * 32);
        #pragma unroll
        for (int c = 0; c < 8; c++) {
            float4 v = src[c];
            xf[c * 4 + 0] = v.x; xf[c * 4 + 1] = v.y; xf[c * 4 + 2] = v.z; xf[c * 4 + 3] = v.w;
        }
    }
    float a6[6] = {0.f, 0.f, 0.f, 0.f, 0.f, 0.f};
    #pragma unroll
    for (int c = 0; c < 8; c++) {
        #pragma unroll
        for (int j = 0; j < 6; j++) {
            float4 p = *(const float4*)&pvs[j * 256 + q8 * 32 + c * 4];
            a6[j] = fmaf(xf[c*4+0], p.x, fmaf(xf[c*4+1], p.y,
                    fmaf(xf[c*4+2], p.z, fmaf(xf[c*4+3], p.w, a6[j]))));
        }
    }
    #pragma unroll
    for (int j = 0; j < 6; j++) {
        a6[j] += __shfl_xor(a6[j], 1);
        a6[j] += __shfl_xor(a6[j], 2);
        a6[j] += __shfl_xor(a6[j], 4);
    }
    if (q8 == 0) {
        #pragma unroll
        for (int j = 0; j < 6; j++) dv[b * 384 + j * 64 + n] = a6[j];
    }
    {
        unsigned short* xd = x0bf + ((size_t)(b * 64 + n)) * DD + q8 * 32;
        #pragma unroll
        for (int k = 0; k < 4; k++) {
            u16x8 u;
            #pragma unroll
            for (int j = 0; j < 8; j++) u[j] = f2bf(xf[k * 8 + j]);
            *(u16x8*)(xd + k * 8) = u;
        }
    }
    {
        const float4* s2 = (const float4*)(emb2_w + (size_t)idx * DD + q8 * 32);
        float4* d2 = (float4*)(out + (size_t)2 * BND + (size_t)(b * 64 + n) * DD + q8 * 32);
        #pragma unroll
        for (int c = 0; c < 8; c++) d2[c] = s2[c];
    }
}

// K2: per batch: masks + 4 softmaxes + 3 small matmuls -> M bf16
__launch_bounds__(512)
__global__ void k2_M(const int* __restrict__ inputs, const int* __restrict__ HT,
                     const float* __restrict__ dv, const float* __restrict__ prep,
                     unsigned short* __restrict__ Mws) {
    __shared__ float Mb[64 * 66];
    __shared__ float An[64 * 66];
    __shared__ float Cb[64 * 66];
    __shared__ float Db[64 * 66];
    __shared__ float dvs[384];
    __shared__ float uu[64];
    __shared__ float db2[192];
    __shared__ unsigned long long mE[64], mN[64];
    const int b = blockIdx.x;
    const int t = threadIdx.x;
    const int lane = t & 63;
    const int w8 = t >> 6;    // 0..7
    const int n8 = t >> 3;    // 0..63
    const int q8 = t & 7;

    if (t < 384) dvs[t] = dv[b * 384 + t];
    for (int i = 0; i < 8; i++) {
        int e = w8 * 8 + i;
        int h = HT[((size_t)b * EE + e) * NN + lane];
        unsigned long long m = __ballot(h > 0);
        if (lane == 0) mE[e] = m;
    }
    __syncthreads();
    if (t < 64) {
        unsigned long long acc = 0ull;
        for (int e = 0; e < 64; e++) acc |= ((mE[e] >> t) & 1ull) << e;
        mN[t] = acc;
    }
    // attE1 -> Mb
    {
        float s1n = lrelu(prep[768] + dvs[lane]);
        for (int i = 0; i < 8; i++) {
            int e = w8 * 8 + i;
            bool msk = (mE[e] >> lane) & 1ull;
            float v = msk ? s1n : NEGV;
            float mx = v;
            #pragma unroll
            for (int o = 32; o > 0; o >>= 1) mx = fmaxf(mx, __shfl_xor(mx, o));
            float p = __expf(v - mx), s = p;
            #pragma unroll
            for (int o = 32; o > 0; o >>= 1) s += __shfl_xor(s, o);
            Mb[e * 66 + lane] = p / s;
        }
    }
    __syncthreads();
    // u1[e] = attE1[e] . dv2
    {
        float s = 0.f;
        #pragma unroll
        for (int c = 0; c < 2; c++) {
            float4 av = *(const float4*)&Mb[n8 * 66 + q8 * 8 + c * 4];
            float4 dd = *(const float4*)&dvs[128 + q8 * 8 + c * 4];
            s = fmaf(av.x, dd.x, fmaf(av.y, dd.y, fmaf(av.z, dd.z, fmaf(av.w, dd.w, s))));
        }
        s += __shfl_xor(s, 1); s += __shfl_xor(s, 2); s += __shfl_xor(s, 4);
        if (q8 == 0) uu[n8] = s;
    }
    __syncthreads();
    // attN1 -> An
    {
        float ul = uu[lane];
        for (int i = 0; i < 8; i++) {
            int n = w8 * 8 + i;
            float sv = lrelu(dvs[64 + n] + ul);
            bool msk = (mN[n] >> lane) & 1ull;
            float v = msk ? sv : NEGV;
            float mx = v;
            #pragma unroll
            for (int o = 32; o > 0; o >>= 1) mx = fmaxf(mx, __shfl_xor(mx, o));
            float p = __expf(v - mx), s = p;
            #pragma unroll
            for (int o = 32; o > 0; o >>= 1) s += __shfl_xor(s, o);
            An[n * 66 + lane] = p / s;
        }
    }
    __syncthreads();
    // C1' = An @ Mb + I -> Cb
    {
        float4 a0 = {0,0,0,0}, a1 = {0,0,0,0};
        for (int k0 = 0; k0 < 64; k0 += 4) {
            float4 wn = *(const float4*)&An[n8 * 66 + k0];
            float wa[4] = {wn.x, wn.y, wn.z, wn.w};
            #pragma unroll
            for (int rr = 0; rr < 4; rr++) {
                float4 b0 = *(const float4*)&Mb[(k0 + rr) * 66 + q8 * 8];
                float4 b1 = *(const float4*)&Mb[(k0 + rr) * 66 + q8 * 8 + 4];
                a0 = fma4(wa[rr], b0, a0);
                a1 = fma4(wa[rr], b1, a1);
            }
        }
        int cbase = q8 * 8;
        a0.x += (cbase + 0 == n8) ? 1.f : 0.f;
        a0.y += (cbase + 1 == n8) ? 1.f : 0.f;
        a0.z += (cbase + 2 == n8) ? 1.f : 0.f;
        a0.w += (cbase + 3 == n8) ? 1.f : 0.f;
        a1.x += (cbase + 4 == n8) ? 1.f : 0.f;
        a1.y += (cbase + 5 == n8) ? 1.f : 0.f;
        a1.z += (cbase + 6 == n8) ? 1.f : 0.f;
        a1.w += (cbase + 7 == n8) ? 1.f : 0.f;
        *(float4*)&Cb[n8 * 66 + q8 * 8] = a0;
        *(float4*)&Cb[n8 * 66 + q8 * 8 + 4] = a1;
    }
    __syncthreads();
    // db2[j] = C1' @ dv[3+j]
    {
        float s0 = 0.f, s1 = 0.f, s2 = 0.f;
        #pragma unroll
        for (int c = 0; c < 2; c++) {
            float4 cv = *(const float4*)&Cb[n8 * 66 + q8 * 8 + c * 4];
            float4 d0 = *(const float4*)&dvs[192 + q8 * 8 + c * 4];
            float4 d1 = *(const float4*)&dvs[256 + q8 * 8 + c * 4];
            float4 d2 = *(const float4*)&dvs[320 + q8 * 8 + c * 4];
            s0 = fmaf(cv.x, d0.x, fmaf(cv.y, d0.y, fmaf(cv.z, d0.z, fmaf(cv.w, d0.w, s0))));
            s1 = fmaf(cv.x, d1.x, fmaf(cv.y, d1.y, fmaf(cv.z, d1.z, fmaf(cv.w, d1.w, s1))));
            s2 = fmaf(cv.x, d2.x, fmaf(cv.y, d2.y, fmaf(cv.z, d2.z, fmaf(cv.w, d2.w, s2))));
        }
        s0 += __shfl_xor(s0, 1); s0 += __shfl_xor(s0, 2); s0 += __shfl_xor(s0, 4);
        s1 += __shfl_xor(s1, 1); s1 += __shfl_xor(s1, 2); s1 += __shfl_xor(s1, 4);
        s2 += __shfl_xor(s2, 1); s2 += __shfl_xor(s2, 2); s2 += __shfl_xor(s2, 4);
        if (q8 == 0) { db2[n8] = s0; db2[64 + n8] = s1; db2[128 + n8] = s2; }
    }
    __syncthreads();
    // attE2 -> Mb
    {
        float s1n = lrelu(prep[1792] + db2[lane]);
        for (int i = 0; i < 8; i++) {
            int e = w8 * 8 + i;
            bool msk = (mE[e] >> lane) & 1ull;
            float v = msk ? s1n : NEGV;
            float mx = v;
            #pragma unroll
            for (int o = 32; o > 0; o >>= 1) mx = fmaxf(mx, __shfl_xor(mx, o));
            float p = __expf(v - mx), s = p;
            #pragma unroll
            for (int o = 32; o > 0; o >>= 1) s += __shfl_xor(s, o);
            Mb[e * 66 + lane] = p / s;
        }
    }
    __syncthreads();
    // u2[e] = attE2[e] . db2[2]
    {
        float s = 0.f;
        #pragma unroll
        for (int c = 0; c < 2; c++) {
            float4 av = *(const float4*)&Mb[n8 * 66 + q8 * 8 + c * 4];
            float4 dd = *(const float4*)&db2[128 + q8 * 8 + c * 4];
            s = fmaf(av.x, dd.x, fmaf(av.y, dd.y, fmaf(av.z, dd.z, fmaf(av.w, dd.w, s))));
        }
        s += __shfl_xor(s, 1); s += __shfl_xor(s, 2); s += __shfl_xor(s, 4);
        if (q8 == 0) uu[n8] = s;
    }
    __syncthreads();
    // attN2 -> An
    {
        float ul = uu[lane];
        for (int i = 0; i < 8; i++) {
            int n = w8 * 8 + i;
            float sv = lrelu(db2[64 + n] + ul);
            bool msk = (mN[n] >> lane) & 1ull;
            float v = msk ? sv : NEGV;
            float mx = v;
            #pragma unroll
            for (int o = 32; o > 0; o >>= 1) mx = fmaxf(mx, __shfl_xor(mx, o));
            float p = __expf(v - mx), s = p;
            #pragma unroll
            for (int o = 32; o > 0; o >>= 1) s += __shfl_xor(s, o);
            An[n * 66 + lane] = p / s;
        }
    }
    __syncthreads();
    // C2 = An @ Mb -> Db
    {
        float4 a0 = {0,0,0,0}, a1 = {0,0,0,0};
        for (int k0 = 0; k0 < 64; k0 += 4) {
            float4 wn = *(const float4*)&An[n8 * 66 + k0];
            float wa[4] = {wn.x, wn.y, wn.z, wn.w};
            #pragma unroll
            for (int rr = 0; rr < 4; rr++) {
                float4 b0 = *(const float4*)&Mb[(k0 + rr) * 66 + q8 * 8];
                float4 b1 = *(const float4*)&Mb[(k0 + rr) * 66 + q8 * 8 + 4];
                a0 = fma4(wa[rr], b0, a0);
                a1 = fma4(wa[rr], b1, a1);
            }
        }
        *(float4*)&Db[n8 * 66 + q8 * 8] = a0;
        *(float4*)&Db[n8 * 66 + q8 * 8 + 4] = a1;
    }
    __syncthreads();
    // M = C2 @ C1' -> bf16 global
    {
        float4 a0 = {0,0,0,0}, a1 = {0,0,0,0};
        for (int k0 = 0; k0 < 64; k0 += 4) {
            float4 wn = *(const float4*)&Db[n8 * 66 + k0];
            float wa[4] = {wn.x, wn.y, wn.z, wn.w};
            #pragma unroll
            for (int rr = 0; rr < 4; rr++) {
                float4 b0 = *(const float4*)&Cb[(k0 + rr) * 66 + q8 * 8];
                float4 b1 = *(const float4*)&Cb[(k0 + rr) * 66 + q8 * 8 + 4];
                a0 = fma4(wa[rr], b0, a0);
                a1 = fma4(wa[rr], b1, a1);
            }
        }
        u16x8 u;
        u[0] = f2bf(a0.x); u[1] = f2bf(a0.y); u[2] = f2bf(a0.z); u[3] = f2bf(a0.w);
        u[4] = f2bf(a1.x); u[5] = f2bf(a1.y); u[6] = f2bf(a1.z); u[7] = f2bf(a1.w);
        *(u16x8*)(Mws + (size_t)b * 4096 + n8 * 64 + q8 * 8) = u;
    }
}

// K3: per half-batch (128 feature cols): Y = x0@w (MFMA), YT bf16, out = M@Y + x0
__launch_bounds__(256)
__global__ void k3_out(const int* __restrict__ inputs,
                       const float* __restrict__ emb_w,
                       const unsigned short* __restrict__ x0bf,
                       const unsigned short* __restrict__ Mws,
                       const unsigned short* __restrict__ wfrag,
                       float* __restrict__ out) {
    __shared__ unsigned short poolA[64 * 264];   // x0 staging; later YT[128][72] overlay
    __shared__ unsigned short Mlds[64 * 68];
    __shared__ int idxs[64];
    unsigned short* YT = poolA;
    const int t = threadIdx.x;
    const int b = blockIdx.x >> 1;
    const int half = blockIdx.x & 1;
    const int c0 = half * 128;
    const int l = t & 63;
    const int w = t >> 6;

    if (t < 64) idxs[t] = inputs[b * 64 + t];
    {
        const u16x8* xsrc = (const u16x8*)(x0bf + (size_t)b * 64 * DD);
        for (int i = t; i < 64 * 32; i += 256) {
            int n = i >> 5, c = i & 31;
            *(u16x8*)&poolA[n * 264 + c * 8] = xsrc[i];
        }
        const u16x8* msrc = (const u16x8*)(Mws + (size_t)b * 4096);
        for (int i = t; i < 512; i += 256) {
            int n = i >> 3, c = i & 7;
            *(u16x8*)&Mlds[n * 68 + c * 8] = msrc[i];
        }
    }
    __syncthreads();

    const int arow = w * 16 + (l & 15);
    const int kh = l >> 4;
    // GEMM1: Y = x0 @ w  (rows w*16.., cols c0..c0+128)
    f4v acc[8];
    #pragma unroll
    for (int nt = 0; nt < 8; nt++) acc[nt] = (f4v){0.f, 0.f, 0.f, 0.f};
    {
        const s8v* wf = (const s8v*)wfrag;
        #pragma unroll
        for (int kc = 0; kc < 8; kc++) {
            s8v a = *(const s8v*)&poolA[arow * 264 + kc * 32 + kh * 8];
            #pragma unroll
            for (int nt = 0; nt < 8; nt++) {
                s8v bv = wf[(size_t)(kc * 16 + (c0 >> 4) + nt) * 64 + l];
                acc[nt] = __builtin_amdgcn_mfma_f32_16x16x32_bf16(a, bv, acc[nt], 0, 0, 0);
            }
        }
    }
    __syncthreads();   // all x0 reads done before YT overlay write

    {
        const int node_base = w * 16 + (l >> 4) * 4;
        #pragma unroll
        for (int nt = 0; nt < 8; nt++) {
            int f = nt * 16 + (l & 15);
            ushort4 u;
            u.x = f2bf(acc[nt][0]); u.y = f2bf(acc[nt][1]);
            u.z = f2bf(acc[nt][2]); u.w = f2bf(acc[nt][3]);
            *(ushort4*)&YT[f * 72 + node_base] = u;
        }
    }
    __syncthreads();

    // GEMM2: out = M @ Y
    f4v acc2[8];
    #pragma unroll
    for (int nt = 0; nt < 8; nt++) acc2[nt] = (f4v){0.f, 0.f, 0.f, 0.f};
    #pragma unroll
    for (int kc = 0; kc < 2; kc++) {
        s8v a = *(const s8v*)&Mlds[arow * 68 + kc * 32 + kh * 8];
        #pragma unroll
        for (int nt = 0; nt < 8; nt++) {
            s8v bv = *(const s8v*)&YT[(nt * 16 + (l & 15)) * 72 + kc * 32 + kh * 8];
            acc2[nt] = __builtin_amdgcn_mfma_f32_16x16x32_bf16(a, bv, acc2[nt], 0, 0, 0);
        }
    }
    // epilogue: + x0 residual (re-gather f32), write x and hidden copies
    {
        const int rbase = w * 16 + (l >> 4) * 4;
        const int cl = l & 15;
        #pragma unroll
        for (int nt = 0; nt < 8; nt++) {
            #pragma unroll
            for (int rg = 0; rg < 4; rg++) {
                int row = rbase + rg;
                int colg = c0 + nt * 16 + cl;
                float r = emb_w[(size_t)idxs[row] * DD + colg];
                float v = acc2[nt][rg] + r;
                size_t o = (size_t)(b * 64 + row) * DD + colg;
                out[o] = v;
                out[BND + o] = v;
            }
        }
    }
}

extern "C" void kernel_launch(void* const* d_in, const int* in_sizes, int n_in,
                              void* d_out, int out_size, void* d_ws, size_t ws_size,
                              hipStream_t stream) {
    const int* inputs = (const int*)d_in[0];
    const int* HT = (const int*)d_in[1];
    const float* emb_w  = (const float*)d_in[4];
    const float* emb2_w = (const float*)d_in[5];
    const float* g1_w2 = (const float*)d_in[6];
    const float* g1_w3 = (const float*)d_in[7];
    const float* g1_a  = (const float*)d_in[8];
    const float* g1_a2 = (const float*)d_in[9];
    const float* g1_wc = (const float*)d_in[10];
    const float* g2_w  = (const float*)d_in[11];
    const float* g2_w2 = (const float*)d_in[12];
    const float* g2_w3 = (const float*)d_in[13];
    const float* g2_a  = (const float*)d_in[14];
    const float* g2_a2 = (const float*)d_in[15];
    const float* g2_wc = (const float*)d_in[16];

    float* out = (float*)d_out;
    float* prep = (float*)((char*)d_ws + WS_PREP);
    unsigned short* wfrag = (unsigned short*)((char*)d_ws + WS_WFRAG);
    float* dv = (float*)((char*)d_ws + WS_DV);
    unsigned short* Mws = (unsigned short*)((char*)d_ws + WS_M);
    unsigned short* x0bf = (unsigned short*)((char*)d_ws + WS_X0);

    prep_kernel<<<1, 256, 0, stream>>>(g1_w2, g1_w3, g1_a, g1_a2, g1_wc,
                                       g2_w2, g2_w3, g2_a, g2_a2, g2_wc,
                                       g2_w, prep);
    pack_w<<<32, 256, 0, stream>>>(g2_w, wfrag);
    k1_stage<<<1024, 256, 0, stream>>>(inputs, emb_w, emb2_w, prep, dv, x0bf, out);
    k2_M<<<512, 512, 0, stream>>>(inputs, HT, dv, prep, Mws);
    k3_out<<<1024, 256, 0, stream>>>(inputs, emb_w, x0bf, Mws, wfrag, out);
}

// Round 5
// 105.858 us; speedup vs baseline: 4.2450x; 1.6417x over previous
//
#include <hip/hip_runtime.h>

#define BB 512
#define NN 64
#define EE 64
#define DD 256
#define BND (BB * NN * DD)
#define NEGV (-9e15f)

typedef __attribute__((ext_vector_type(8))) short s8v;
typedef __attribute__((ext_vector_type(4))) float f4v;
typedef __attribute__((ext_vector_type(8))) unsigned short u16x8;

__device__ __forceinline__ unsigned short f2bf(float f) {
    unsigned int x = __float_as_uint(f);
    x = x + 0x7fffu + ((x >> 16) & 1u);   // RNE
    return (unsigned short)(x >> 16);
}
__device__ __forceinline__ float bf2f(unsigned short u) {
    return __uint_as_float(((unsigned int)u) << 16);
}
__device__ __forceinline__ float lrelu(float v) { return v > 0.f ? v : 0.2f * v; }

// ws byte offsets
#define WS_PREP  0          // 2048 f32 (8KB)
#define WS_P3B   8192       // 256 f32
#define WS_WFRAG 12288      // 65536 bf16 (128KB)
#define WS_DV    143360     // 512*384 f32
#define WS_M     929792     // 512*4096 bf16

// prep layout (floats): [0)p1a [256)p2a [512)p3a [768]c0a [1024)p1b [1280)p2b [1536)wp3b [1792]c0b

// 16 blocks: blk<8 layer a rows blk*32.., blk>=8 layer b. Coalesced row reads, 8-lane reduce.
__global__ void prep_dots(const float* __restrict__ w2a, const float* __restrict__ w3a,
                          const float* __restrict__ aa, const float* __restrict__ a2a,
                          const float* __restrict__ wca,
                          const float* __restrict__ w2b, const float* __restrict__ w3b,
                          const float* __restrict__ ab, const float* __restrict__ a2b,
                          const float* __restrict__ wcb,
                          float* __restrict__ prep, float* __restrict__ p3b_ws) {
    const int t = threadIdx.x;
    const int blk = blockIdx.x;
    const int layer = blk >> 3;
    const int r0 = (blk & 7) * 32;
    __shared__ float vhi[256], v2lo[256], v2hi[256], red[256];
    const float* w2 = layer ? w2b : w2a;
    const float* w3 = layer ? w3b : w3a;
    const float* av = layer ? ab : aa;
    const float* a2 = layer ? a2b : a2a;
    vhi[t] = av[256 + t];
    v2lo[t] = a2[t];
    v2hi[t] = a2[256 + t];
    __syncthreads();
    const int row = r0 + (t >> 3), q = t & 7;
    const float* w2r = w2 + (size_t)row * DD + q * 32;
    const float* w3r = w3 + (size_t)row * DD + q * 32;
    float s1 = 0.f, s2 = 0.f, s3 = 0.f;
    #pragma unroll
    for (int c = 0; c < 8; c++) {
        float4 v = *(const float4*)&w2r[c * 4];
        float4 u = *(const float4*)&w3r[c * 4];
        float4 p1 = *(const float4*)&vhi[q * 32 + c * 4];
        float4 p2 = *(const float4*)&v2lo[q * 32 + c * 4];
        float4 p3 = *(const float4*)&v2hi[q * 32 + c * 4];
        s1 = fmaf(v.x, p1.x, fmaf(v.y, p1.y, fmaf(v.z, p1.z, fmaf(v.w, p1.w, s1))));
        s2 = fmaf(v.x, p2.x, fmaf(v.y, p2.y, fmaf(v.z, p2.z, fmaf(v.w, p2.w, s2))));
        s3 = fmaf(u.x, p3.x, fmaf(u.y, p3.y, fmaf(u.z, p3.z, fmaf(u.w, p3.w, s3))));
    }
    s1 += __shfl_xor(s1, 1); s1 += __shfl_xor(s1, 2); s1 += __shfl_xor(s1, 4);
    s2 += __shfl_xor(s2, 1); s2 += __shfl_xor(s2, 2); s2 += __shfl_xor(s2, 4);
    s3 += __shfl_xor(s3, 1); s3 += __shfl_xor(s3, 2); s3 += __shfl_xor(s3, 4);
    if (q == 0) {
        if (layer == 0) { prep[row] = s1; prep[256 + row] = s2; prep[512 + row] = s3; }
        else { prep[1024 + row] = s1; prep[1280 + row] = s2; p3b_ws[row] = s3; }
    }
    if ((blk & 7) == 0) {
        red[t] = layer ? (wcb[t] * ab[t]) : (wca[t] * aa[t]);
        __syncthreads();
        for (int o = 128; o > 0; o >>= 1) { if (t < o) red[t] += red[t + o]; __syncthreads(); }
        if (t == 0) prep[layer ? 1792 : 768] = red[0];
    }
}

// blocks 0..7: wp3b = wtr @ p3b ; blocks 8..39: pack g2_w into MFMA B-fragments
__global__ void prep2_pack(const float* __restrict__ wtr, const float* __restrict__ p3b_ws,
                           float* __restrict__ prep, unsigned short* __restrict__ wfrag) {
    const int t = threadIdx.x, blk = blockIdx.x;
    __shared__ float p3[256];
    if (blk < 8) {
        p3[t] = p3b_ws[t];
        __syncthreads();
        const int row = blk * 32 + (t >> 3), q = t & 7;
        const float* wr = wtr + (size_t)row * DD + q * 32;
        float s = 0.f;
        #pragma unroll
        for (int c = 0; c < 8; c++) {
            float4 v = *(const float4*)&wr[c * 4];
            float4 p = *(const float4*)&p3[q * 32 + c * 4];
            s = fmaf(v.x, p.x, fmaf(v.y, p.y, fmaf(v.z, p.z, fmaf(v.w, p.w, s))));
        }
        s += __shfl_xor(s, 1); s += __shfl_xor(s, 2); s += __shfl_xor(s, 4);
        if (q == 0) prep[1536 + row] = s;
    } else {
        int gid = (blk - 8) * 256 + t;      // 0..8191
        int l = gid & 63, frag = gid >> 6;
        int kc = frag >> 4, nt = frag & 15;
        int kb = kc * 32 + (l >> 4) * 8;
        int n = nt * 16 + (l & 15);
        u16x8 u;
        #pragma unroll
        for (int j = 0; j < 8; j++) u[j] = f2bf(wtr[(size_t)(kb + j) * DD + n]);
        *(u16x8*)(wfrag + (size_t)gid * 8) = u;
    }
}

// K1: per half-batch: emb gather -> dv (6 dots) ; nodes2 copy
__launch_bounds__(256)
__global__ void k1_stage(const int* __restrict__ inputs,
                         const float* __restrict__ emb_w, const float* __restrict__ emb2_w,
                         const float* __restrict__ prep,
                         float* __restrict__ dv, float* __restrict__ out) {
    __shared__ float pvs[6 * 256];
    const int t = threadIdx.x;
    const int b = blockIdx.x >> 1;
    const int half = blockIdx.x & 1;
    {
        const int off[6] = {0, 256, 512, 1024, 1280, 1536};
        #pragma unroll
        for (int j = 0; j < 6; j++) pvs[j * 256 + t] = prep[off[j] + t];
    }
    const int n = half * 32 + (t >> 3);
    const int q8 = t & 7;
    const int idx = inputs[b * 64 + n];
    __syncthreads();
    float a6[6] = {0.f, 0.f, 0.f, 0.f, 0.f, 0.f};
    {
        const float4* src = (const float4*)(emb_w + (size_t)idx * DD + q8 * 32);
        #pragma unroll
        for (int c = 0; c < 8; c++) {
            float4 v = src[c];
            #pragma unroll
            for (int j = 0; j < 6; j++) {
                float4 p = *(const float4*)&pvs[j * 256 + q8 * 32 + c * 4];
                a6[j] = fmaf(v.x, p.x, fmaf(v.y, p.y, fmaf(v.z, p.z, fmaf(v.w, p.w, a6[j]))));
            }
        }
    }
    #pragma unroll
    for (int j = 0; j < 6; j++) {
        a6[j] += __shfl_xor(a6[j], 1);
        a6[j] += __shfl_xor(a6[j], 2);
        a6[j] += __shfl_xor(a6[j], 4);
    }
    if (q8 == 0) {
        #pragma unroll
        for (int j = 0; j < 6; j++) dv[b * 384 + j * 64 + n] = a6[j];
    }
    {
        const float4* s2 = (const float4*)(emb2_w + (size_t)idx * DD + q8 * 32);
        float4* d2 = (float4*)(out + (size_t)2 * BND + (size_t)(b * 64 + n) * DD + q8 * 32);
        #pragma unroll
        for (int c = 0; c < 8; c++) d2[c] = s2[c];
    }
}

// K2: masks + 4 softmaxes (u-dots fused) + 3 MFMA 64^3 matmuls -> M bf16
__launch_bounds__(512)
__global__ void k2_M(const int* __restrict__ HT, const float* __restrict__ dv,
                     const float* __restrict__ prep, unsigned short* __restrict__ Mws) {
    __shared__ unsigned short ET[64 * 72];    // attE^T (node-major), layer1 then layer2
    __shared__ unsigned short AN[64 * 72];    // attN row-major, layer1 then layer2
    __shared__ unsigned short C1T[64 * 72];   // C1'^T
    __shared__ unsigned short CR[64 * 72];    // C1' row-major; later C2 row-major
    __shared__ float dvs[384];
    __shared__ float uu[64];
    __shared__ float db2[192];
    __shared__ unsigned long long mE[64], mN[64];
    const int b = blockIdx.x, t = threadIdx.x;
    const int lane = t & 63, w8 = t >> 6;
    const int l15 = lane & 15, lh = lane >> 4;

    if (t < 384) dvs[t] = dv[b * 384 + t];
    #pragma unroll
    for (int i = 0; i < 8; i++) {
        int e = w8 * 8 + i;
        int h = HT[((size_t)b * EE + e) * NN + lane];
        unsigned long long m = __ballot(h > 0);
        if (lane == 0) mE[e] = m;
    }
    __syncthreads();
    if (t < 64) {
        unsigned long long acc = 0ull;
        for (int e = 0; e < 64; e++) acc |= ((mE[e] >> t) & 1ull) << e;
        mN[t] = acc;
    }
    // P1: attE1 softmax + u1 -> ET, uu
    {
        float s1n = lrelu(prep[768] + dvs[lane]);
        float d2 = dvs[128 + lane];
        for (int i = 0; i < 8; i++) {
            int e = w8 * 8 + i;
            bool mk = (mE[e] >> lane) & 1ull;
            float v = mk ? s1n : NEGV;
            float mx = v;
            #pragma unroll
            for (int o = 32; o > 0; o >>= 1) mx = fmaxf(mx, __shfl_xor(mx, o));
            float p = __expf(v - mx);
            float s = p, sd = p * d2;
            #pragma unroll
            for (int o = 32; o > 0; o >>= 1) { s += __shfl_xor(s, o); sd += __shfl_xor(sd, o); }
            ET[lane * 72 + e] = f2bf(p / s);
            if (lane == 0) uu[e] = sd / s;
        }
    }
    __syncthreads();
    // P2: attN1 softmax -> AN
    {
        float ul = uu[lane];
        for (int i = 0; i < 8; i++) {
            int n = w8 * 8 + i;
            float sv = lrelu(dvs[64 + n] + ul);
            bool mk = (mN[n] >> lane) & 1ull;
            float v = mk ? sv : NEGV;
            float mx = v;
            #pragma unroll
            for (int o = 32; o > 0; o >>= 1) mx = fmaxf(mx, __shfl_xor(mx, o));
            float p = __expf(v - mx), s = p;
            #pragma unroll
            for (int o = 32; o > 0; o >>= 1) s += __shfl_xor(s, o);
            AN[n * 72 + lane] = f2bf(p / s);
        }
    }
    __syncthreads();
    const int wr = (w8 & 3) * 16;
    const int wc = (w8 >> 2) * 32;
    // P3: C1' = AN @ attE1 + I -> C1T + CR (bf16)
    {
        f4v acc0 = {0.f,0.f,0.f,0.f}, acc1 = {0.f,0.f,0.f,0.f};
        #pragma unroll
        for (int kc = 0; kc < 2; kc++) {
            s8v a  = *(const s8v*)&AN[(wr + l15) * 72 + kc * 32 + lh * 8];
            s8v b0 = *(const s8v*)&ET[(wc + l15) * 72 + kc * 32 + lh * 8];
            s8v b1 = *(const s8v*)&ET[(wc + 16 + l15) * 72 + kc * 32 + lh * 8];
            acc0 = __builtin_amdgcn_mfma_f32_16x16x32_bf16(a, b0, acc0, 0, 0, 0);
            acc1 = __builtin_amdgcn_mfma_f32_16x16x32_bf16(a, b1, acc1, 0, 0, 0);
        }
        const int row0 = wr + lh * 4;
        {
            int col = wc + l15;
            ushort4 uT;
            #pragma unroll
            for (int rg = 0; rg < 4; rg++) {
                unsigned short bb = f2bf(acc0[rg] + ((row0 + rg) == col ? 1.f : 0.f));
                ((unsigned short*)&uT)[rg] = bb;
                CR[(row0 + rg) * 72 + col] = bb;
            }
            *(ushort4*)&C1T[col * 72 + row0] = uT;
        }
        {
            int col = wc + 16 + l15;
            ushort4 uT;
            #pragma unroll
            for (int rg = 0; rg < 4; rg++) {
                unsigned short bb = f2bf(acc1[rg] + ((row0 + rg) == col ? 1.f : 0.f));
                ((unsigned short*)&uT)[rg] = bb;
                CR[(row0 + rg) * 72 + col] = bb;
            }
            *(ushort4*)&C1T[col * 72 + row0] = uT;
        }
    }
    __syncthreads();
    // P4: db2[j] = C1' @ dvs[3+j]
    {
        int n8 = t >> 3, q8 = t & 7;
        u16x8 cv = *(const u16x8*)&CR[n8 * 72 + q8 * 8];
        float s0 = 0.f, s1 = 0.f, s2 = 0.f;
        #pragma unroll
        for (int j = 0; j < 8; j++) {
            float c = bf2f(cv[j]);
            s0 = fmaf(c, dvs[192 + q8 * 8 + j], s0);
            s1 = fmaf(c, dvs[256 + q8 * 8 + j], s1);
            s2 = fmaf(c, dvs[320 + q8 * 8 + j], s2);
        }
        s0 += __shfl_xor(s0, 1); s0 += __shfl_xor(s0, 2); s0 += __shfl_xor(s0, 4);
        s1 += __shfl_xor(s1, 1); s1 += __shfl_xor(s1, 2); s1 += __shfl_xor(s1, 4);
        s2 += __shfl_xor(s2, 1); s2 += __shfl_xor(s2, 2); s2 += __shfl_xor(s2, 4);
        if (q8 == 0) { db2[n8] = s0; db2[64 + n8] = s1; db2[128 + n8] = s2; }
    }
    __syncthreads();
    // P5: attE2 softmax + u2 -> ET, uu
    {
        float s1n = lrelu(prep[1792] + db2[lane]);
        float d2 = db2[128 + lane];
        for (int i = 0; i < 8; i++) {
            int e = w8 * 8 + i;
            bool mk = (mE[e] >> lane) & 1ull;
            float v = mk ? s1n : NEGV;
            float mx = v;
            #pragma unroll
            for (int o = 32; o > 0; o >>= 1) mx = fmaxf(mx, __shfl_xor(mx, o));
            float p = __expf(v - mx);
            float s = p, sd = p * d2;
            #pragma unroll
            for (int o = 32; o > 0; o >>= 1) { s += __shfl_xor(s, o); sd += __shfl_xor(sd, o); }
            ET[lane * 72 + e] = f2bf(p / s);
            if (lane == 0) uu[e] = sd / s;
        }
    }
    __syncthreads();
    // P6: attN2 softmax -> AN
    {
        float ul = uu[lane];
        for (int i = 0; i < 8; i++) {
            int n = w8 * 8 + i;
            float sv = lrelu(db2[64 + n] + ul);
            bool mk = (mN[n] >> lane) & 1ull;
            float v = mk ? sv : NEGV;
            float mx = v;
            #pragma unroll
            for (int o = 32; o > 0; o >>= 1) mx = fmaxf(mx, __shfl_xor(mx, o));
            float p = __expf(v - mx), s = p;
            #pragma unroll
            for (int o = 32; o > 0; o >>= 1) s += __shfl_xor(s, o);
            AN[n * 72 + lane] = f2bf(p / s);
        }
    }
    __syncthreads();
    // P7: C2 = AN @ attE2 -> CR row-major (bf16)
    {
        f4v acc0 = {0.f,0.f,0.f,0.f}, acc1 = {0.f,0.f,0.f,0.f};
        #pragma unroll
        for (int kc = 0; kc < 2; kc++) {
            s8v a  = *(const s8v*)&AN[(wr + l15) * 72 + kc * 32 + lh * 8];
            s8v b0 = *(const s8v*)&ET[(wc + l15) * 72 + kc * 32 + lh * 8];
            s8v b1 = *(const s8v*)&ET[(wc + 16 + l15) * 72 + kc * 32 + lh * 8];
            acc0 = __builtin_amdgcn_mfma_f32_16x16x32_bf16(a, b0, acc0, 0, 0, 0);
            acc1 = __builtin_amdgcn_mfma_f32_16x16x32_bf16(a, b1, acc1, 0, 0, 0);
        }
        const int row0 = wr + lh * 4;
        #pragma unroll
        for (int rg = 0; rg < 4; rg++) {
            CR[(row0 + rg) * 72 + wc + l15] = f2bf(acc0[rg]);
            CR[(row0 + rg) * 72 + wc + 16 + l15] = f2bf(acc1[rg]);
        }
    }
    __syncthreads();
    // P8: M = C2 @ C1' -> global bf16
    {
        f4v acc0 = {0.f,0.f,0.f,0.f}, acc1 = {0.f,0.f,0.f,0.f};
        #pragma unroll
        for (int kc = 0; kc < 2; kc++) {
            s8v a  = *(const s8v*)&CR[(wr + l15) * 72 + kc * 32 + lh * 8];
            s8v b0 = *(const s8v*)&C1T[(wc + l15) * 72 + kc * 32 + lh * 8];
            s8v b1 = *(const s8v*)&C1T[(wc + 16 + l15) * 72 + kc * 32 + lh * 8];
            acc0 = __builtin_amdgcn_mfma_f32_16x16x32_bf16(a, b0, acc0, 0, 0, 0);
            acc1 = __builtin_amdgcn_mfma_f32_16x16x32_bf16(a, b1, acc1, 0, 0, 0);
        }
        const int row0 = wr + lh * 4;
        unsigned short* md = Mws + (size_t)b * 4096;
        #pragma unroll
        for (int rg = 0; rg < 4; rg++) {
            md[(row0 + rg) * 64 + wc + l15] = f2bf(acc0[rg]);
            md[(row0 + rg) * 64 + wc + 16 + l15] = f2bf(acc1[rg]);
        }
    }
}

// K3: per half-batch (128 cols): stage x0 bf16 from emb, Y = x0@w (MFMA), YT, out = M@Y + x0
__launch_bounds__(256)
__global__ void k3_out(const int* __restrict__ inputs,
                       const float* __restrict__ emb_w,
                       const unsigned short* __restrict__ Mws,
                       const unsigned short* __restrict__ wfrag,
                       float* __restrict__ out) {
    __shared__ unsigned short poolA[64 * 264];   // x0 bf16 staging; later YT[128][72]
    __shared__ unsigned short Mlds[64 * 68];
    __shared__ int idxs[64];
    unsigned short* YT = poolA;
    const int t = threadIdx.x;
    const int b = blockIdx.x >> 1;
    const int half = blockIdx.x & 1;
    const int c0 = half * 128;
    const int l = t & 63;
    const int w = t >> 6;

    if (t < 64) idxs[t] = inputs[b * 64 + t];
    __syncthreads();
    {
        const int n = t >> 2, q = t & 3;
        const float4* src = (const float4*)(emb_w + (size_t)idxs[n] * DD + q * 64);
        #pragma unroll
        for (int c = 0; c < 16; c++) {
            float4 v = src[c];
            ushort4 u;
            u.x = f2bf(v.x); u.y = f2bf(v.y); u.z = f2bf(v.z); u.w = f2bf(v.w);
            *(ushort4*)&poolA[n * 264 + q * 64 + c * 4] = u;
        }
        const u16x8* msrc = (const u16x8*)(Mws + (size_t)b * 4096);
        for (int i = t; i < 512; i += 256) {
            int n2 = i >> 3, c2 = i & 7;
            *(u16x8*)&Mlds[n2 * 68 + c2 * 8] = msrc[i];
        }
    }
    __syncthreads();

    const int arow = w * 16 + (l & 15);
    const int kh = l >> 4;
    // GEMM1: Y = x0 @ w
    f4v acc[8];
    #pragma unroll
    for (int nt = 0; nt < 8; nt++) acc[nt] = (f4v){0.f, 0.f, 0.f, 0.f};
    {
        const s8v* wf = (const s8v*)wfrag;
        #pragma unroll
        for (int kc = 0; kc < 8; kc++) {
            s8v a = *(const s8v*)&poolA[arow * 264 + kc * 32 + kh * 8];
            #pragma unroll
            for (int nt = 0; nt < 8; nt++) {
                s8v bv = wf[(size_t)(kc * 16 + (c0 >> 4) + nt) * 64 + l];
                acc[nt] = __builtin_amdgcn_mfma_f32_16x16x32_bf16(a, bv, acc[nt], 0, 0, 0);
            }
        }
    }
    __syncthreads();   // x0 reads done before YT overlay
    {
        const int node_base = w * 16 + (l >> 4) * 4;
        #pragma unroll
        for (int nt = 0; nt < 8; nt++) {
            int f = nt * 16 + (l & 15);
            ushort4 u;
            u.x = f2bf(acc[nt][0]); u.y = f2bf(acc[nt][1]);
            u.z = f2bf(acc[nt][2]); u.w = f2bf(acc[nt][3]);
            *(ushort4*)&YT[f * 72 + node_base] = u;
        }
    }
    __syncthreads();
    // GEMM2: out = M @ Y
    f4v acc2[8];
    #pragma unroll
    for (int nt = 0; nt < 8; nt++) acc2[nt] = (f4v){0.f, 0.f, 0.f, 0.f};
    #pragma unroll
    for (int kc = 0; kc < 2; kc++) {
        s8v a = *(const s8v*)&Mlds[arow * 68 + kc * 32 + kh * 8];
        #pragma unroll
        for (int nt = 0; nt < 8; nt++) {
            s8v bv = *(const s8v*)&YT[(nt * 16 + (l & 15)) * 72 + kc * 32 + kh * 8];
            acc2[nt] = __builtin_amdgcn_mfma_f32_16x16x32_bf16(a, bv, acc2[nt], 0, 0, 0);
        }
    }
    // epilogue: residual re-gather (L1/L2-hot) + dual write
    {
        const int rbase = w * 16 + (l >> 4) * 4;
        const int cl = l & 15;
        #pragma unroll
        for (int nt = 0; nt < 8; nt++) {
            #pragma unroll
            for (int rg = 0; rg < 4; rg++) {
                int row = rbase + rg;
                int colg = c0 + nt * 16 + cl;
                float r = emb_w[(size_t)idxs[row] * DD + colg];
                float v = acc2[nt][rg] + r;
                size_t o = (size_t)(b * 64 + row) * DD + colg;
                out[o] = v;
                out[BND + o] = v;
            }
        }
    }
}

extern "C" void kernel_launch(void* const* d_in, const int* in_sizes, int n_in,
                              void* d_out, int out_size, void* d_ws, size_t ws_size,
                              hipStream_t stream) {
    const int* inputs = (const int*)d_in[0];
    const int* HT = (const int*)d_in[1];
    const float* emb_w  = (const float*)d_in[4];
    const float* emb2_w = (const float*)d_in[5];
    const float* g1_w2 = (const float*)d_in[6];
    const float* g1_w3 = (const float*)d_in[7];
    const float* g1_a  = (const float*)d_in[8];
    const float* g1_a2 = (const float*)d_in[9];
    const float* g1_wc = (const float*)d_in[10];
    const float* g2_w  = (const float*)d_in[11];
    const float* g2_w2 = (const float*)d_in[12];
    const float* g2_w3 = (const float*)d_in[13];
    const float* g2_a  = (const float*)d_in[14];
    const float* g2_a2 = (const float*)d_in[15];
    const float* g2_wc = (const float*)d_in[16];

    float* out = (float*)d_out;
    float* prep = (float*)((char*)d_ws + WS_PREP);
    float* p3b_ws = (float*)((char*)d_ws + WS_P3B);
    unsigned short* wfrag = (unsigned short*)((char*)d_ws + WS_WFRAG);
    float* dv = (float*)((char*)d_ws + WS_DV);
    unsigned short* Mws = (unsigned short*)((char*)d_ws + WS_M);

    prep_dots<<<16, 256, 0, stream>>>(g1_w2, g1_w3, g1_a, g1_a2, g1_wc,
                                      g2_w2, g2_w3, g2_a, g2_a2, g2_wc,
                                      prep, p3b_ws);
    prep2_pack<<<40, 256, 0, stream>>>(g2_w, p3b_ws, prep, wfrag);
    k1_stage<<<1024, 256, 0, stream>>>(inputs, emb_w, emb2_w, prep, dv, out);
    k2_M<<<512, 512, 0, stream>>>(HT, dv, prep, Mws);
    k3_out<<<1024, 256, 0, stream>>>(inputs, emb_w, Mws, wfrag, out);
}

// Round 6
// 78.543 us; speedup vs baseline: 5.7213x; 1.3478x over previous
//
#include <hip/hip_runtime.h>

#define BB 512
#define NN 64
#define EE 64
#define DD 256
#define BND (BB * NN * DD)
#define NEGV (-9e15f)
#define SA 68

typedef __attribute__((ext_vector_type(8))) short s8v;
typedef __attribute__((ext_vector_type(4))) float f4v;
typedef __attribute__((ext_vector_type(8))) unsigned short u16x8;

__device__ __forceinline__ unsigned short f2bf(float f) {
    unsigned int x = __float_as_uint(f);
    x = x + 0x7fffu + ((x >> 16) & 1u);   // RNE
    return (unsigned short)(x >> 16);
}
__device__ __forceinline__ float bf2f(unsigned short u) {
    return __uint_as_float(((unsigned int)u) << 16);
}
__device__ __forceinline__ float lrelu(float v) { return v > 0.f ? v : 0.2f * v; }

// ws byte offsets
#define WS_PREP  0          // 2048 f32 (8KB)
#define WS_P3B   8192       // 256 f32
#define WS_WFRAG 12288      // 65536 bf16 (128KB)

// prep layout (floats): [0)p1a [256)p2a [512)p3a [768]c0a [1024)p1b [1280)p2b [1536)wp3b [1792]c0b
__global__ void prep_dots(const float* __restrict__ w2a, const float* __restrict__ w3a,
                          const float* __restrict__ aa, const float* __restrict__ a2a,
                          const float* __restrict__ wca,
                          const float* __restrict__ w2b, const float* __restrict__ w3b,
                          const float* __restrict__ ab, const float* __restrict__ a2b,
                          const float* __restrict__ wcb,
                          float* __restrict__ prep, float* __restrict__ p3b_ws) {
    const int t = threadIdx.x;
    const int blk = blockIdx.x;
    const int layer = blk >> 3;
    const int r0 = (blk & 7) * 32;
    __shared__ float vhi[256], v2lo[256], v2hi[256], red[256];
    const float* w2 = layer ? w2b : w2a;
    const float* w3 = layer ? w3b : w3a;
    const float* av = layer ? ab : aa;
    const float* a2 = layer ? a2b : a2a;
    vhi[t] = av[256 + t];
    v2lo[t] = a2[t];
    v2hi[t] = a2[256 + t];
    __syncthreads();
    const int row = r0 + (t >> 3), q = t & 7;
    const float* w2r = w2 + (size_t)row * DD + q * 32;
    const float* w3r = w3 + (size_t)row * DD + q * 32;
    float s1 = 0.f, s2 = 0.f, s3 = 0.f;
    #pragma unroll
    for (int c = 0; c < 8; c++) {
        float4 v = *(const float4*)&w2r[c * 4];
        float4 u = *(const float4*)&w3r[c * 4];
        float4 p1 = *(const float4*)&vhi[q * 32 + c * 4];
        float4 p2 = *(const float4*)&v2lo[q * 32 + c * 4];
        float4 p3 = *(const float4*)&v2hi[q * 32 + c * 4];
        s1 = fmaf(v.x, p1.x, fmaf(v.y, p1.y, fmaf(v.z, p1.z, fmaf(v.w, p1.w, s1))));
        s2 = fmaf(v.x, p2.x, fmaf(v.y, p2.y, fmaf(v.z, p2.z, fmaf(v.w, p2.w, s2))));
        s3 = fmaf(u.x, p3.x, fmaf(u.y, p3.y, fmaf(u.z, p3.z, fmaf(u.w, p3.w, s3))));
    }
    s1 += __shfl_xor(s1, 1); s1 += __shfl_xor(s1, 2); s1 += __shfl_xor(s1, 4);
    s2 += __shfl_xor(s2, 1); s2 += __shfl_xor(s2, 2); s2 += __shfl_xor(s2, 4);
    s3 += __shfl_xor(s3, 1); s3 += __shfl_xor(s3, 2); s3 += __shfl_xor(s3, 4);
    if (q == 0) {
        if (layer == 0) { prep[row] = s1; prep[256 + row] = s2; prep[512 + row] = s3; }
        else { prep[1024 + row] = s1; prep[1280 + row] = s2; p3b_ws[row] = s3; }
    }
    if ((blk & 7) == 0) {
        red[t] = layer ? (wcb[t] * ab[t]) : (wca[t] * aa[t]);
        __syncthreads();
        for (int o = 128; o > 0; o >>= 1) { if (t < o) red[t] += red[t + o]; __syncthreads(); }
        if (t == 0) prep[layer ? 1792 : 768] = red[0];
    }
}

// blocks 0..7: wp3b = wtr @ p3b ; blocks 8..39: pack g2_w into MFMA B-fragments
__global__ void prep2_pack(const float* __restrict__ wtr, const float* __restrict__ p3b_ws,
                           float* __restrict__ prep, unsigned short* __restrict__ wfrag) {
    const int t = threadIdx.x, blk = blockIdx.x;
    __shared__ float p3[256];
    if (blk < 8) {
        p3[t] = p3b_ws[t];
        __syncthreads();
        const int row = blk * 32 + (t >> 3), q = t & 7;
        const float* wr = wtr + (size_t)row * DD + q * 32;
        float s = 0.f;
        #pragma unroll
        for (int c = 0; c < 8; c++) {
            float4 v = *(const float4*)&wr[c * 4];
            float4 p = *(const float4*)&p3[q * 32 + c * 4];
            s = fmaf(v.x, p.x, fmaf(v.y, p.y, fmaf(v.z, p.z, fmaf(v.w, p.w, s))));
        }
        s += __shfl_xor(s, 1); s += __shfl_xor(s, 2); s += __shfl_xor(s, 4);
        if (q == 0) prep[1536 + row] = s;
    } else {
        int gid = (blk - 8) * 256 + t;      // 0..8191
        int l = gid & 63, frag = gid >> 6;
        int kc = frag >> 4, nt = frag & 15;
        int kb = kc * 32 + (l >> 4) * 8;
        int n = nt * 16 + (l & 15);
        u16x8 u;
        #pragma unroll
        for (int j = 0; j < 8; j++) u[j] = f2bf(wtr[(size_t)(kb + j) * DD + n]);
        *(u16x8*)(wfrag + (size_t)gid * 8) = u;
    }
}

// One block per batch: gather+dots -> softmaxes -> M (all in LDS) -> 2 MFMA GEMMs -> out.
__launch_bounds__(512, 4)
__global__ void mega(const int* __restrict__ inputs, const int* __restrict__ HT,
                     const float* __restrict__ emb_w, const float* __restrict__ emb2_w,
                     const float* __restrict__ prep, const unsigned short* __restrict__ wfrag,
                     float* __restrict__ out) {
    __shared__ unsigned short bufA[256 * SA];   // x0bf [64][264] -> YT [256][68]
    __shared__ unsigned short bufE[64 * SA];    // attE1 -> attE2 -> M
    __shared__ unsigned short bufN[64 * SA];    // attN1 -> attN2 -> C2
    __shared__ unsigned short bufT[64 * SA];    // C1'^T
    __shared__ float pvs[6 * 256];
    __shared__ float dvs[384];
    __shared__ float uu[64];
    __shared__ float db2[192];
    __shared__ unsigned long long mE[64], mN[64];
    __shared__ int idxs[64];

    const int b = blockIdx.x;
    const int t = threadIdx.x;
    const int lane = t & 63;
    const int w8 = t >> 6;                 // wave 0..7
    const int l15 = lane & 15, lh = lane >> 4;

    // ---- P0: pvs + idxs ----
    for (int i = t; i < 1536; i += 512) {
        const int off[6] = {0, 256, 512, 1024, 1280, 1536};
        pvs[i] = prep[off[i >> 8] + (i & 255)];
    }
    if (t < 64) idxs[t] = inputs[b * 64 + t];
    __syncthreads();

    // ---- P1: stage x0 (f32 -> dots f32 + bf16 LDS) ; HT masks ; nodes2 copy ----
    {
        const int rw = t >> 3, q8 = t & 7;
        const float* src = emb_w + (size_t)idxs[rw] * DD + q8 * 32;
        float a6[6] = {0.f, 0.f, 0.f, 0.f, 0.f, 0.f};
        #pragma unroll
        for (int c = 0; c < 8; c++) {
            float4 v = *(const float4*)&src[c * 4];
            ushort4 u;
            u.x = f2bf(v.x); u.y = f2bf(v.y); u.z = f2bf(v.z); u.w = f2bf(v.w);
            *(ushort4*)&bufA[rw * 264 + q8 * 32 + c * 4] = u;
            #pragma unroll
            for (int j = 0; j < 6; j++) {
                float4 p = *(const float4*)&pvs[j * 256 + q8 * 32 + c * 4];
                a6[j] = fmaf(v.x, p.x, fmaf(v.y, p.y, fmaf(v.z, p.z, fmaf(v.w, p.w, a6[j]))));
            }
        }
        #pragma unroll
        for (int j = 0; j < 6; j++) {
            a6[j] += __shfl_xor(a6[j], 1);
            a6[j] += __shfl_xor(a6[j], 2);
            a6[j] += __shfl_xor(a6[j], 4);
        }
        if (q8 == 0) {
            #pragma unroll
            for (int j = 0; j < 6; j++) dvs[j * 64 + rw] = a6[j];
        }
    }
    #pragma unroll
    for (int i = 0; i < 8; i++) {
        int e = w8 * 8 + i;
        int h = HT[((size_t)b * EE + e) * NN + lane];
        unsigned long long m = __ballot(h > 0);
        if (lane == 0) mE[e] = m;
    }
    for (int i = t; i < 64 * 64; i += 512) {
        int n = i >> 6, c = i & 63;
        float4 v = ((const float4*)(emb2_w + (size_t)idxs[n] * DD))[c];
        ((float4*)(out + (size_t)2 * BND + (size_t)(b * 64 + n) * DD))[c] = v;
    }
    __syncthreads();

    // ---- P2: mN ; attE1 softmax + u1 -> bufE, uu ----
    if (t < 64) {
        unsigned long long acc = 0ull;
        for (int e = 0; e < 64; e++) acc |= ((mE[e] >> t) & 1ull) << e;
        mN[t] = acc;
    }
    {
        float s1n = lrelu(prep[768] + dvs[lane]);
        float d2 = dvs[128 + lane];
        for (int i = 0; i < 8; i++) {
            int e = w8 * 8 + i;
            bool mk = (mE[e] >> lane) & 1ull;
            float v = mk ? s1n : NEGV;
            float mx = v;
            #pragma unroll
            for (int o = 32; o > 0; o >>= 1) mx = fmaxf(mx, __shfl_xor(mx, o));
            float p = __expf(v - mx);
            float s = p, sd = p * d2;
            #pragma unroll
            for (int o = 32; o > 0; o >>= 1) { s += __shfl_xor(s, o); sd += __shfl_xor(sd, o); }
            bufE[lane * SA + e] = f2bf(p / s);
            if (lane == 0) uu[e] = sd / s;
        }
    }
    __syncthreads();

    // ---- P3: attN1 -> bufN ----
    {
        float ul = uu[lane];
        for (int i = 0; i < 8; i++) {
            int n = w8 * 8 + i;
            float sv = lrelu(dvs[64 + n] + ul);
            bool mk = (mN[n] >> lane) & 1ull;
            float v = mk ? sv : NEGV;
            float mx = v;
            #pragma unroll
            for (int o = 32; o > 0; o >>= 1) mx = fmaxf(mx, __shfl_xor(mx, o));
            float p = __expf(v - mx), s = p;
            #pragma unroll
            for (int o = 32; o > 0; o >>= 1) s += __shfl_xor(s, o);
            bufN[n * SA + lane] = f2bf(p / s);
        }
    }
    __syncthreads();

    const int wr = (w8 & 3) * 16;
    const int wc = (w8 >> 2) * 32;
    const int row0 = wr + lh * 4;

    // ---- P4: C1' = attN1 @ attE1 + I -> bufT (C1T, col-major) ----
    {
        f4v a0 = {0.f,0.f,0.f,0.f}, a1 = {0.f,0.f,0.f,0.f};
        #pragma unroll
        for (int kc = 0; kc < 2; kc++) {
            s8v a  = *(const s8v*)&bufN[(wr + l15) * SA + kc * 32 + lh * 8];
            s8v b0 = *(const s8v*)&bufE[(wc + l15) * SA + kc * 32 + lh * 8];
            s8v b1 = *(const s8v*)&bufE[(wc + 16 + l15) * SA + kc * 32 + lh * 8];
            a0 = __builtin_amdgcn_mfma_f32_16x16x32_bf16(a, b0, a0, 0, 0, 0);
            a1 = __builtin_amdgcn_mfma_f32_16x16x32_bf16(a, b1, a1, 0, 0, 0);
        }
        int col0 = wc + l15, col1 = wc + 16 + l15;
        ushort4 u0, u1;
        #pragma unroll
        for (int rg = 0; rg < 4; rg++) {
            ((unsigned short*)&u0)[rg] = f2bf(a0[rg] + ((row0 + rg) == col0 ? 1.f : 0.f));
            ((unsigned short*)&u1)[rg] = f2bf(a1[rg] + ((row0 + rg) == col1 ? 1.f : 0.f));
        }
        *(ushort4*)&bufT[col0 * SA + row0] = u0;
        *(ushort4*)&bufT[col1 * SA + row0] = u1;
    }
    __syncthreads();

    // ---- P5: db2[j] = C1' @ dvs[3+j]  (column reads of C1T) ----
    {
        const int n8 = t >> 3, q8 = t & 7;
        float s0 = 0.f, s1 = 0.f, s2 = 0.f;
        #pragma unroll
        for (int jj = 0; jj < 8; jj++) {
            int j = q8 * 8 + jj;
            float c = bf2f(bufT[j * SA + n8]);
            s0 = fmaf(c, dvs[192 + j], s0);
            s1 = fmaf(c, dvs[256 + j], s1);
            s2 = fmaf(c, dvs[320 + j], s2);
        }
        s0 += __shfl_xor(s0, 1); s0 += __shfl_xor(s0, 2); s0 += __shfl_xor(s0, 4);
        s1 += __shfl_xor(s1, 1); s1 += __shfl_xor(s1, 2); s1 += __shfl_xor(s1, 4);
        s2 += __shfl_xor(s2, 1); s2 += __shfl_xor(s2, 2); s2 += __shfl_xor(s2, 4);
        if (q8 == 0) { db2[n8] = s0; db2[64 + n8] = s1; db2[128 + n8] = s2; }
    }
    __syncthreads();

    // ---- P6: attE2 softmax + u2 -> bufE (attE1 dead), uu ----
    {
        float s1n = lrelu(prep[1792] + db2[lane]);
        float d2 = db2[128 + lane];
        for (int i = 0; i < 8; i++) {
            int e = w8 * 8 + i;
            bool mk = (mE[e] >> lane) & 1ull;
            float v = mk ? s1n : NEGV;
            float mx = v;
            #pragma unroll
            for (int o = 32; o > 0; o >>= 1) mx = fmaxf(mx, __shfl_xor(mx, o));
            float p = __expf(v - mx);
            float s = p, sd = p * d2;
            #pragma unroll
            for (int o = 32; o > 0; o >>= 1) { s += __shfl_xor(s, o); sd += __shfl_xor(sd, o); }
            bufE[lane * SA + e] = f2bf(p / s);
            if (lane == 0) uu[e] = sd / s;
        }
    }
    __syncthreads();

    // ---- P7: attN2 -> bufN (attN1 dead) ----
    {
        float ul = uu[lane];
        for (int i = 0; i < 8; i++) {
            int n = w8 * 8 + i;
            float sv = lrelu(db2[64 + n] + ul);
            bool mk = (mN[n] >> lane) & 1ull;
            float v = mk ? sv : NEGV;
            float mx = v;
            #pragma unroll
            for (int o = 32; o > 0; o >>= 1) mx = fmaxf(mx, __shfl_xor(mx, o));
            float p = __expf(v - mx), s = p;
            #pragma unroll
            for (int o = 32; o > 0; o >>= 1) s += __shfl_xor(s, o);
            bufN[n * SA + lane] = f2bf(p / s);
        }
    }
    __syncthreads();

    // ---- P8: C2 = attN2 @ attE2 -> regs ; barrier ; -> bufN (overwrite) ----
    {
        f4v a0 = {0.f,0.f,0.f,0.f}, a1 = {0.f,0.f,0.f,0.f};
        #pragma unroll
        for (int kc = 0; kc < 2; kc++) {
            s8v a  = *(const s8v*)&bufN[(wr + l15) * SA + kc * 32 + lh * 8];
            s8v b0 = *(const s8v*)&bufE[(wc + l15) * SA + kc * 32 + lh * 8];
            s8v b1 = *(const s8v*)&bufE[(wc + 16 + l15) * SA + kc * 32 + lh * 8];
            a0 = __builtin_amdgcn_mfma_f32_16x16x32_bf16(a, b0, a0, 0, 0, 0);
            a1 = __builtin_amdgcn_mfma_f32_16x16x32_bf16(a, b1, a1, 0, 0, 0);
        }
        __syncthreads();
        #pragma unroll
        for (int rg = 0; rg < 4; rg++) {
            bufN[(row0 + rg) * SA + wc + l15] = f2bf(a0[rg]);
            bufN[(row0 + rg) * SA + wc + 16 + l15] = f2bf(a1[rg]);
        }
    }
    __syncthreads();

    // ---- P9: M = C2 @ C1' -> bufE (attE2 dead), row-major ----
    {
        f4v a0 = {0.f,0.f,0.f,0.f}, a1 = {0.f,0.f,0.f,0.f};
        #pragma unroll
        for (int kc = 0; kc < 2; kc++) {
            s8v a  = *(const s8v*)&bufN[(wr + l15) * SA + kc * 32 + lh * 8];
            s8v b0 = *(const s8v*)&bufT[(wc + l15) * SA + kc * 32 + lh * 8];
            s8v b1 = *(const s8v*)&bufT[(wc + 16 + l15) * SA + kc * 32 + lh * 8];
            a0 = __builtin_amdgcn_mfma_f32_16x16x32_bf16(a, b0, a0, 0, 0, 0);
            a1 = __builtin_amdgcn_mfma_f32_16x16x32_bf16(a, b1, a1, 0, 0, 0);
        }
        __syncthreads();   // all P9 reads of bufE(attE2)? (attE2 last read in P8; safe) + bufN reads done
        #pragma unroll
        for (int rg = 0; rg < 4; rg++) {
            bufE[(row0 + rg) * SA + wc + l15] = f2bf(a0[rg]);
            bufE[(row0 + rg) * SA + wc + 16 + l15] = f2bf(a1[rg]);
        }
    }
    __syncthreads();

    // ---- P10: GEMM1 Y = x0 @ w (A from bufA, B from global wfrag) -> YT overlay ----
    const int cb8 = (w8 >> 2) * 8;   // col-tile base (0 or 8)
    {
        f4v acc[8];
        #pragma unroll
        for (int nt = 0; nt < 8; nt++) acc[nt] = (f4v){0.f, 0.f, 0.f, 0.f};
        const s8v* wf = (const s8v*)wfrag;
        #pragma unroll
        for (int kc = 0; kc < 8; kc++) {
            s8v a = *(const s8v*)&bufA[(wr + l15) * 264 + kc * 32 + lh * 8];
            #pragma unroll
            for (int nt = 0; nt < 8; nt++) {
                s8v bv = wf[(size_t)(kc * 16 + cb8 + nt) * 64 + lane];
                acc[nt] = __builtin_amdgcn_mfma_f32_16x16x32_bf16(a, bv, acc[nt], 0, 0, 0);
            }
        }
        __syncthreads();   // x0bf dead -> YT overlay
        #pragma unroll
        for (int nt = 0; nt < 8; nt++) {
            int feat = (cb8 + nt) * 16 + l15;
            ushort4 u;
            u.x = f2bf(acc[nt][0]); u.y = f2bf(acc[nt][1]);
            u.z = f2bf(acc[nt][2]); u.w = f2bf(acc[nt][3]);
            *(ushort4*)&bufA[feat * SA + row0] = u;
        }
    }
    __syncthreads();

    // ---- P11: out = M @ Y + x0 ----
    {
        f4v acc2[8];
        #pragma unroll
        for (int nt = 0; nt < 8; nt++) acc2[nt] = (f4v){0.f, 0.f, 0.f, 0.f};
        #pragma unroll
        for (int kc = 0; kc < 2; kc++) {
            s8v a = *(const s8v*)&bufE[(wr + l15) * SA + kc * 32 + lh * 8];
            #pragma unroll
            for (int nt = 0; nt < 8; nt++) {
                s8v bv = *(const s8v*)&bufA[((cb8 + nt) * 16 + l15) * SA + kc * 32 + lh * 8];
                acc2[nt] = __builtin_amdgcn_mfma_f32_16x16x32_bf16(a, bv, acc2[nt], 0, 0, 0);
            }
        }
        #pragma unroll
        for (int nt = 0; nt < 8; nt++) {
            #pragma unroll
            for (int rg = 0; rg < 4; rg++) {
                int row = row0 + rg;
                int colg = (cb8 + nt) * 16 + l15;
                float r = emb_w[(size_t)idxs[row] * DD + colg];
                float v = acc2[nt][rg] + r;
                size_t o = (size_t)(b * 64 + row) * DD + colg;
                out[o] = v;
                out[BND + o] = v;
            }
        }
    }
}

extern "C" void kernel_launch(void* const* d_in, const int* in_sizes, int n_in,
                              void* d_out, int out_size, void* d_ws, size_t ws_size,
                              hipStream_t stream) {
    const int* inputs = (const int*)d_in[0];
    const int* HT = (const int*)d_in[1];
    const float* emb_w  = (const float*)d_in[4];
    const float* emb2_w = (const float*)d_in[5];
    const float* g1_w2 = (const float*)d_in[6];
    const float* g1_w3 = (const float*)d_in[7];
    const float* g1_a  = (const float*)d_in[8];
    const float* g1_a2 = (const float*)d_in[9];
    const float* g1_wc = (const float*)d_in[10];
    const float* g2_w  = (const float*)d_in[11];
    const float* g2_w2 = (const float*)d_in[12];
    const float* g2_w3 = (const float*)d_in[13];
    const float* g2_a  = (const float*)d_in[14];
    const float* g2_a2 = (const float*)d_in[15];
    const float* g2_wc = (const float*)d_in[16];

    float* out = (float*)d_out;
    float* prep = (float*)((char*)d_ws + WS_PREP);
    float* p3b_ws = (float*)((char*)d_ws + WS_P3B);
    unsigned short* wfrag = (unsigned short*)((char*)d_ws + WS_WFRAG);

    prep_dots<<<16, 256, 0, stream>>>(g1_w2, g1_w3, g1_a, g1_a2, g1_wc,
                                      g2_w2, g2_w3, g2_a, g2_a2, g2_wc,
                                      prep, p3b_ws);
    prep2_pack<<<40, 256, 0, stream>>>(g2_w, p3b_ws, prep, wfrag);
    mega<<<BB, 512, 0, stream>>>(inputs, HT, emb_w, emb2_w, prep, wfrag, out);
}